// Round 2
// baseline (6197.217 us; speedup 1.0000x reference)
//
#include <hip/hip_runtime.h>

// ---------- bf16 helpers ----------
typedef unsigned short bf16u;

__device__ __forceinline__ float bf2f(bf16u u) {
    return __uint_as_float(((unsigned)u) << 16);
}
__device__ __forceinline__ bf16u f2bf(float f) {
    unsigned u = __float_as_uint(f);
    unsigned r = (u + 0x7fffu + ((u >> 16) & 1u)) >> 16;
    return (bf16u)r;
}
__device__ __forceinline__ float sigmoidf_(float x) {
    return 1.0f / (1.0f + __expf(-x));
}

// ---------- dtype detection ----------
// flag=1 -> raw inputs are fp32; flag=0 -> raw inputs are bf16.
// Genuine bf16 N(0,1) data has no exp==0xFF patterns; fp32 data misread as
// ushorts has ~0.4% of low-halves with exp==0xFF.
__global__ void init_flag_kernel(int* flag) {
    if (threadIdx.x == 0 && blockIdx.x == 0) *flag = 0;
}
__global__ __launch_bounds__(256) void detect_kernel(
    const void* x, int nelem, int* flag)
{
    const int scan = nelem < (1 << 20) ? nelem : (1 << 20);
    const bf16u* p = (const bf16u*)x;
    int bad = 0;
    for (int j = blockIdx.x * 256 + threadIdx.x; j < scan; j += 65536) {
        unsigned u = p[j];
        if ((u & 0x7F80u) == 0x7F80u) bad = 1;
    }
    if (bad) atomicOr(flag, 1);
}

// ---------- polymorphic convert: raw (bf16 or fp32) -> fp32 ----------
__global__ __launch_bounds__(256) void cvt_kernel(
    const void* __restrict__ in, float* __restrict__ out, int n,
    const int* __restrict__ flagp)
{
    const int f32 = *flagp;
    const int i = blockIdx.x * 256 + threadIdx.x;
    if (i >= n) return;
    if (f32) out[i] = ((const float*)in)[i];
    else     out[i] = bf2f(((const bf16u*)in)[i]);
}

// ---------- LayerNorm ----------
// One block (256 thr) per row. D in {512,1024}.
// IN_RAW: input is a raw tensor (dtype per flag); else fp32 ws buffer.
// OUT_RAW: output is d_out (dtype per flag); else fp32 ws buffer.
template <int D, bool IN_RAW, bool OUT_RAW, bool SILU, bool COPY>
__global__ __launch_bounds__(256) void ln_kernel(
    const void* __restrict__ in_, const void* __restrict__ gvec,
    const void* __restrict__ bvec, void* __restrict__ out_,
    float* __restrict__ copy_out, const int* __restrict__ flagp)
{
    constexpr int VPT = D / 256;
    const int f32 = *flagp;
    const int row = blockIdx.x;
    const int tid = threadIdx.x;
    const size_t base = (size_t)row * D;
    float x[VPT];
    if (IN_RAW) {
        if (f32) {
            const float* in = (const float*)in_;
            #pragma unroll
            for (int i = 0; i < VPT; ++i) x[i] = in[base + tid + i * 256];
        } else {
            const bf16u* in = (const bf16u*)in_;
            #pragma unroll
            for (int i = 0; i < VPT; ++i) x[i] = bf2f(in[base + tid + i * 256]);
        }
    } else {
        const float* in = (const float*)in_;
        #pragma unroll
        for (int i = 0; i < VPT; ++i) x[i] = in[base + tid + i * 256];
    }
    float s = 0.f, q = 0.f;
    #pragma unroll
    for (int i = 0; i < VPT; ++i) { s += x[i]; q += x[i] * x[i]; }
    __shared__ float red[10];
    #pragma unroll
    for (int off = 32; off; off >>= 1) {
        s += __shfl_down(s, off, 64);
        q += __shfl_down(q, off, 64);
    }
    const int lane = tid & 63, wv = tid >> 6;
    if (lane == 0) { red[wv] = s; red[4 + wv] = q; }
    __syncthreads();
    if (tid == 0) {
        float ts = red[0] + red[1] + red[2] + red[3];
        float tq = red[4] + red[5] + red[6] + red[7];
        float mean = ts / (float)D;
        float var = tq / (float)D - mean * mean;
        red[8] = mean;
        red[9] = rsqrtf(var + 1e-5f);
    }
    __syncthreads();
    const float mean = red[8], rstd = red[9];
    #pragma unroll
    for (int i = 0; i < VPT; ++i) {
        const int c = tid + i * 256;
        float gv, bv;
        if (f32) {
            gv = ((const float*)gvec)[c];
            bv = ((const float*)bvec)[c];
        } else {
            gv = bf2f(((const bf16u*)gvec)[c]);
            bv = bf2f(((const bf16u*)bvec)[c]);
        }
        float v = (x[i] - mean) * rstd * gv + bv;
        if (SILU) v *= sigmoidf_(v);
        if (OUT_RAW) {
            if (f32) ((float*)out_)[base + c] = v;
            else     ((bf16u*)out_)[base + c] = f2bf(v);
        } else {
            ((float*)out_)[base + c] = v;
        }
        if (COPY) copy_out[base + c] = x[i];
    }
}

// ---------- generic GEMM: C = res + alpha * act(A @ W + bias) ----------
// A fp32 [M,K] row-major, W raw [K,N] row-major (dtype per flag),
// bias raw [N] or null, res fp32 [M,N] or null, C fp32 [M,N].
// act: 0=none, 1=silu. 64x64 tile, BK=16, 256 threads, 4x4 per thread.
__global__ __launch_bounds__(256) void gemm_kernel(
    const float* __restrict__ A, const void* __restrict__ W,
    const void* __restrict__ bias, const float* __restrict__ res,
    float* __restrict__ C, int M, int N, int K, float alpha, int act,
    const int* __restrict__ flagp)
{
    __shared__ float As[16][64];
    __shared__ float Bs[16][64];
    const int f32 = *flagp;
    const int tid = threadIdx.x;
    const int bm = blockIdx.y * 64, bn = blockIdx.x * 64;
    const int tx = tid & 15, ty = tid >> 4;
    const int arow = tid >> 2, acol = (tid & 3) * 4;
    const int brow = tid >> 4, bcol = (tid & 15) * 4;
    const float* aptr = A + (size_t)(bm + arow) * K + acol;
    float acc[4][4] = {};
    for (int k0 = 0; k0 < K; k0 += 16) {
        float4 av = *(const float4*)(aptr + k0);
        const size_t widx = (size_t)(brow + k0) * N + bn + bcol;
        float4 bfv;
        if (f32) {
            bfv = *(const float4*)((const float*)W + widx);
        } else {
            ushort4 bv = *(const ushort4*)((const bf16u*)W + widx);
            bfv.x = bf2f(bv.x); bfv.y = bf2f(bv.y);
            bfv.z = bf2f(bv.z); bfv.w = bf2f(bv.w);
        }
        __syncthreads();
        As[acol + 0][arow] = av.x;
        As[acol + 1][arow] = av.y;
        As[acol + 2][arow] = av.z;
        As[acol + 3][arow] = av.w;
        *(float4*)&Bs[brow][bcol] = bfv;
        __syncthreads();
        #pragma unroll
        for (int kk = 0; kk < 16; ++kk) {
            float4 a4 = *(const float4*)&As[kk][ty * 4];
            float4 b4 = *(const float4*)&Bs[kk][tx * 4];
            float ar[4] = {a4.x, a4.y, a4.z, a4.w};
            float br[4] = {b4.x, b4.y, b4.z, b4.w};
            #pragma unroll
            for (int i = 0; i < 4; ++i)
                #pragma unroll
                for (int j = 0; j < 4; ++j)
                    acc[i][j] = fmaf(ar[i], br[j], acc[i][j]);
        }
    }
    float bias4[4] = {0.f, 0.f, 0.f, 0.f};
    if (bias) {
        if (f32) {
            #pragma unroll
            for (int j = 0; j < 4; ++j) bias4[j] = ((const float*)bias)[bn + tx * 4 + j];
        } else {
            #pragma unroll
            for (int j = 0; j < 4; ++j) bias4[j] = bf2f(((const bf16u*)bias)[bn + tx * 4 + j]);
        }
    }
    #pragma unroll
    for (int i = 0; i < 4; ++i) {
        const int m = bm + ty * 4 + i;
        const size_t off = (size_t)m * N + bn + tx * 4;
        float v[4];
        #pragma unroll
        for (int j = 0; j < 4; ++j) {
            float t = acc[i][j] + bias4[j];
            if (act == 1) t *= sigmoidf_(t);
            v[j] = t * alpha;
        }
        if (res) {
            float4 r4 = *(const float4*)(res + off);
            v[0] += r4.x; v[1] += r4.y; v[2] += r4.z; v[3] += r4.w;
        }
        float4 o4 = {v[0], v[1], v[2], v[3]};
        *(float4*)(C + off) = o4;
    }
}

// ---------- fused rel-pos attention ----------
// Grid: (T/8, H, B). Block 256. 8 query rows x full 1024 keys.
// rel_shift(bd_raw)[i,j]:  j<=i  -> bd_raw[i, T-1-i+j]
//                          j==i+1-> 0
//                          j>=i+2-> bd_raw[i+1, j-i-2]
__global__ __launch_bounds__(256) void attn_kernel(
    const float* __restrict__ Q, const float* __restrict__ Kb,
    const float* __restrict__ V, const float* __restrict__ P,
    const void* __restrict__ bu, const void* __restrict__ bvb,
    float* __restrict__ O, const int* __restrict__ flagp)
{
    constexpr int T = 1024, DD = 512;
    const float scale = 0.125f;
    __shared__ float s[8][1024];
    __shared__ float qu[8][64];
    __shared__ float qv[9][64];
    __shared__ float pp[8][64];
    const int f32 = *flagp;
    const int tid = threadIdx.x;
    const int i0 = blockIdx.x * 8;
    const int h = blockIdx.y, b = blockIdx.z;
    const int hoff = h * 64;

    for (int e = tid; e < 576; e += 256) {
        const int r = e >> 6, d = e & 63;
        const int gi = i0 + r;
        float qval = (gi < T) ? Q[((size_t)b * T + gi) * DD + hoff + d] : 0.0f;
        float bus, bvs;
        if (f32) {
            bus = ((const float*)bu)[hoff + d];
            bvs = ((const float*)bvb)[hoff + d];
        } else {
            bus = bf2f(((const bf16u*)bu)[hoff + d]);
            bvs = bf2f(((const bf16u*)bvb)[hoff + d]);
        }
        if (r < 8) qu[r][d] = qval + bus;
        qv[r][d] = qval + bvs;
    }
    __syncthreads();

    // scores
    for (int e = tid; e < 8 * 1024; e += 256) {
        const int r = e >> 10, j = e & 1023;
        const int i = i0 + r;
        const float* krow = Kb + ((size_t)b * T + j) * DD + hoff;
        float qk = 0.f;
        #pragma unroll
        for (int d4 = 0; d4 < 64; d4 += 4) {
            float4 kv = *(const float4*)(krow + d4);
            qk += qu[r][d4] * kv.x + qu[r][d4 + 1] * kv.y +
                  qu[r][d4 + 2] * kv.z + qu[r][d4 + 3] * kv.w;
        }
        float bd = 0.f;
        int qvr, c;
        if (j <= i)          { qvr = r;     c = (T - 1) - i + j; }
        else if (j == i + 1) { qvr = -1;    c = 0; }
        else                 { qvr = r + 1; c = j - i - 2; }
        if (qvr >= 0) {
            const float* prow = P + (size_t)c * DD + hoff;
            #pragma unroll
            for (int d4 = 0; d4 < 64; d4 += 4) {
                float4 pv = *(const float4*)(prow + d4);
                bd += qv[qvr][d4] * pv.x + qv[qvr][d4 + 1] * pv.y +
                      qv[qvr][d4 + 2] * pv.z + qv[qvr][d4 + 3] * pv.w;
            }
        }
        s[r][j] = (qk + bd) * scale;
    }
    __syncthreads();

    // softmax per row (32 threads / row)
    {
        const int r = tid >> 5, sub = tid & 31;
        float m = -1e30f;
        for (int j = sub; j < 1024; j += 32) m = fmaxf(m, s[r][j]);
        #pragma unroll
        for (int off = 16; off; off >>= 1) m = fmaxf(m, __shfl_xor(m, off, 32));
        float l = 0.f;
        for (int j = sub; j < 1024; j += 32) {
            float e = __expf(s[r][j] - m);
            s[r][j] = e;
            l += e;
        }
        #pragma unroll
        for (int off = 16; off; off >>= 1) l += __shfl_xor(l, off, 32);
        const float inv = 1.0f / l;
        for (int j = sub; j < 1024; j += 32) s[r][j] *= inv;
    }
    __syncthreads();

    // O = attn @ V
    {
        const int half = tid >> 7, w = tid & 127;
        const int r = w >> 4, d4 = (w & 15) * 4;
        float a0 = 0, a1 = 0, a2 = 0, a3 = 0;
        const float* vrow = V + ((size_t)b * T + half * 512) * DD + hoff + d4;
        for (int j = 0; j < 512; ++j) {
            const float p = s[r][half * 512 + j];
            float4 vv = *(const float4*)(vrow + (size_t)j * DD);
            a0 = fmaf(p, vv.x, a0); a1 = fmaf(p, vv.y, a1);
            a2 = fmaf(p, vv.z, a2); a3 = fmaf(p, vv.w, a3);
        }
        if (half == 1) {
            pp[r][d4] = a0; pp[r][d4 + 1] = a1; pp[r][d4 + 2] = a2; pp[r][d4 + 3] = a3;
        }
        __syncthreads();
        if (half == 0) {
            float4 o4;
            o4.x = a0 + pp[r][d4];
            o4.y = a1 + pp[r][d4 + 1];
            o4.z = a2 + pp[r][d4 + 2];
            o4.w = a3 + pp[r][d4 + 3];
            *(float4*)(O + ((size_t)b * T + i0 + r) * DD + hoff + d4) = o4;
        }
    }
}

// ---------- GLU ----------
__global__ __launch_bounds__(256) void glu_kernel(
    const float* __restrict__ H, float* __restrict__ out, int total)
{
    const int idx = blockIdx.x * 256 + threadIdx.x;
    if (idx >= total) return;
    const int m = idx >> 10, c = idx & 1023;
    const float a = H[(size_t)m * 2048 + c];
    const float g = H[(size_t)m * 2048 + 1024 + c];
    out[idx] = a * sigmoidf_(g);
}

// ---------- depthwise conv, K=33, pad 16 ----------
__global__ __launch_bounds__(256) void dwconv_kernel(
    const float* __restrict__ in, const void* __restrict__ wp,
    float* __restrict__ out, const int* __restrict__ flagp)
{
    const int f32 = *flagp;
    const int m = blockIdx.x;          // b*T + t
    const int b = m >> 10, t = m & 1023;
    for (int c = threadIdx.x; c < 1024; c += 256) {
        float wloc[33];
        if (f32) {
            #pragma unroll
            for (int k = 0; k < 33; ++k) wloc[k] = ((const float*)wp)[c * 33 + k];
        } else {
            #pragma unroll
            for (int k = 0; k < 33; ++k) wloc[k] = bf2f(((const bf16u*)wp)[c * 33 + k]);
        }
        float acc = 0.f;
        #pragma unroll
        for (int k = 0; k < 33; ++k) {
            const int tt = t + k - 16;
            if (tt >= 0 && tt < 1024)
                acc = fmaf(in[((size_t)(b << 10) + tt) * 1024 + c], wloc[k], acc);
        }
        out[(size_t)m * 1024 + c] = acc;
    }
}

static inline void launch_gemm(const float* A, const void* W, const void* bias,
                               const float* res, float* C, int M, int N, int K,
                               float alpha, int act, const int* flagp,
                               hipStream_t stream)
{
    dim3 grid(N / 64, M / 64);
    gemm_kernel<<<grid, 256, 0, stream>>>(A, W, bias, res, C, M, N, K, alpha, act, flagp);
}

extern "C" void kernel_launch(void* const* d_in, const int* in_sizes, int n_in,
                              void* d_out, int out_size, void* d_ws, size_t ws_size,
                              hipStream_t stream)
{
    const void* x       = d_in[0];
    const void* pos_emb = d_in[1];
    const void* ln1_g   = d_in[2];
    const void* ln1_b   = d_in[3];
    const void* ffn1_w1 = d_in[4];
    const void* ffn1_b1 = d_in[5];
    const void* ffn1_w2 = d_in[6];
    const void* ffn1_b2 = d_in[7];
    const void* lnq_g   = d_in[8];
    const void* lnq_b   = d_in[9];
    const void* lnk_g   = d_in[10];
    const void* lnk_b   = d_in[11];
    const void* lnv_g   = d_in[12];
    const void* lnv_b   = d_in[13];
    const void* wq      = d_in[14];
    const void* wk      = d_in[15];
    const void* wv      = d_in[16];
    const void* wpos    = d_in[17];
    const void* pbu     = d_in[18];
    const void* pbv     = d_in[19];
    const void* wfc     = d_in[20];
    const void* cln_g   = d_in[21];
    const void* cln_b   = d_in[22];
    const void* pw1     = d_in[23];
    const void* dw_w    = d_in[24];
    const void* bn_g    = d_in[25];
    const void* bn_b    = d_in[26];
    const void* pw2     = d_in[27];
    const void* ln2_g   = d_in[28];
    const void* ln2_b   = d_in[29];
    const void* ffn2_w1 = d_in[30];
    const void* ffn2_b1 = d_in[31];
    const void* ffn2_w2 = d_in[32];
    const void* ffn2_b2 = d_in[33];
    const void* lnf_g   = d_in[34];
    const void* lnf_b   = d_in[35];

    const int BT = 8192;           // B*T rows
    float* ws = (float*)d_ws;
    float* act  = ws;              // [8192,512]
    float* tmp  = ws +  4194304;   // [8192,512]  LN outputs / attn out
    float* hbuf = ws +  8388608;   // [8192,2048]
    float* qb   = ws + 25165824;   // [8192,512]
    float* kb   = ws + 29360128;   // [8192,512]
    float* vb   = ws + 33554432;   // [8192,512]
    float* pb   = ws + 37748736;   // [1024,512]
    int*   flagp = (int*)(ws + 38273024);
    float* ob   = tmp;             // attn output reuses tmp
    float* glu  = qb;              // [8192,1024] spans qb..kb
    float* dwo  = hbuf;            // [8192,1024]

    // ---- dtype detection ----
    init_flag_kernel<<<1, 64, 0, stream>>>(flagp);
    detect_kernel<<<256, 256, 0, stream>>>(x, in_sizes[0], flagp);

    // ---- P = pos_emb @ wpos (tmp as fp32 staging) ----
    cvt_kernel<<<2048, 256, 0, stream>>>(pos_emb, tmp, 524288, flagp);
    launch_gemm(tmp, wpos, nullptr, nullptr, pb, 1024, 512, 512, 1.0f, 0, flagp, stream);

    // ---- FFN1 half-step: act = x + 0.5*ffn(x) ----
    ln_kernel<512, true, false, false, true><<<BT, 256, 0, stream>>>(x, ln1_g, ln1_b, tmp, act, flagp);
    launch_gemm(tmp, ffn1_w1, ffn1_b1, nullptr, hbuf, BT, 2048, 512, 1.0f, 1, flagp, stream);
    launch_gemm(hbuf, ffn1_w2, ffn1_b2, act, act, BT, 512, 2048, 0.5f, 0, flagp, stream);

    // ---- MHSA ----
    ln_kernel<512, false, false, false, false><<<BT, 256, 0, stream>>>(act, lnq_g, lnq_b, tmp, nullptr, flagp);
    launch_gemm(tmp, wq, nullptr, nullptr, qb, BT, 512, 512, 1.0f, 0, flagp, stream);
    ln_kernel<512, false, false, false, false><<<BT, 256, 0, stream>>>(act, lnk_g, lnk_b, tmp, nullptr, flagp);
    launch_gemm(tmp, wk, nullptr, nullptr, kb, BT, 512, 512, 1.0f, 0, flagp, stream);
    ln_kernel<512, false, false, false, false><<<BT, 256, 0, stream>>>(act, lnv_g, lnv_b, tmp, nullptr, flagp);
    launch_gemm(tmp, wv, nullptr, nullptr, vb, BT, 512, 512, 1.0f, 0, flagp, stream);

    attn_kernel<<<dim3(128, 8, 8), 256, 0, stream>>>(qb, kb, vb, pb, pbu, pbv, ob, flagp);
    launch_gemm(ob, wfc, nullptr, act, act, BT, 512, 512, 1.0f, 0, flagp, stream);

    // ---- convolution module ----
    ln_kernel<512, false, false, false, false><<<BT, 256, 0, stream>>>(act, cln_g, cln_b, tmp, nullptr, flagp);
    launch_gemm(tmp, pw1, nullptr, nullptr, hbuf, BT, 2048, 512, 1.0f, 0, flagp, stream);
    glu_kernel<<<32768, 256, 0, stream>>>(hbuf, glu, 8388608);
    dwconv_kernel<<<BT, 256, 0, stream>>>(glu, dw_w, dwo, flagp);
    ln_kernel<1024, false, false, true, false><<<BT, 256, 0, stream>>>(dwo, bn_g, bn_b, glu, nullptr, flagp);
    launch_gemm(glu, pw2, nullptr, act, act, BT, 512, 1024, 1.0f, 0, flagp, stream);

    // ---- FFN2 half-step ----
    ln_kernel<512, false, false, false, false><<<BT, 256, 0, stream>>>(act, ln2_g, ln2_b, tmp, nullptr, flagp);
    launch_gemm(tmp, ffn2_w1, ffn2_b1, nullptr, hbuf, BT, 2048, 512, 1.0f, 1, flagp, stream);
    launch_gemm(hbuf, ffn2_w2, ffn2_b2, act, act, BT, 512, 2048, 0.5f, 0, flagp, stream);

    // ---- final LN -> out (dtype per flag) ----
    ln_kernel<512, false, true, false, false><<<BT, 256, 0, stream>>>(act, lnf_g, lnf_b, d_out, nullptr, flagp);
}

// Round 3
// 3157.974 us; speedup vs baseline: 1.9624x; 1.9624x over previous
//
#include <hip/hip_runtime.h>

// ---------- bf16 helpers ----------
typedef unsigned short bf16u;

__device__ __forceinline__ float bf2f(bf16u u) {
    return __uint_as_float(((unsigned)u) << 16);
}
__device__ __forceinline__ bf16u f2bf(float f) {
    unsigned u = __float_as_uint(f);
    unsigned r = (u + 0x7fffu + ((u >> 16) & 1u)) >> 16;
    return (bf16u)r;
}
__device__ __forceinline__ float sigmoidf_(float x) {
    return 1.0f / (1.0f + __expf(-x));
}

// ---------- dtype detection ----------
// flag=1 -> raw inputs are fp32; flag=0 -> raw inputs are bf16.
__global__ void init_flag_kernel(int* flag) {
    if (threadIdx.x == 0 && blockIdx.x == 0) *flag = 0;
}
__global__ __launch_bounds__(256) void detect_kernel(
    const void* x, int nelem, int* flag)
{
    const int scan = nelem < (1 << 20) ? nelem : (1 << 20);
    const bf16u* p = (const bf16u*)x;
    int bad = 0;
    for (int j = blockIdx.x * 256 + threadIdx.x; j < scan; j += 65536) {
        unsigned u = p[j];
        if ((u & 0x7F80u) == 0x7F80u) bad = 1;
    }
    if (bad) atomicOr(flag, 1);
}

// ---------- polymorphic convert: raw (bf16 or fp32) -> fp32 ----------
__global__ __launch_bounds__(256) void cvt_kernel(
    const void* __restrict__ in, float* __restrict__ out, int n,
    const int* __restrict__ flagp)
{
    const int f32 = *flagp;
    const int i = blockIdx.x * 256 + threadIdx.x;
    if (i >= n) return;
    if (f32) out[i] = ((const float*)in)[i];
    else     out[i] = bf2f(((const bf16u*)in)[i]);
}

// ---------- LayerNorm ----------
template <int D, bool IN_RAW, bool OUT_RAW, bool SILU, bool COPY>
__global__ __launch_bounds__(256) void ln_kernel(
    const void* __restrict__ in_, const void* __restrict__ gvec,
    const void* __restrict__ bvec, void* __restrict__ out_,
    float* __restrict__ copy_out, const int* __restrict__ flagp)
{
    constexpr int VPT = D / 256;
    const int f32 = *flagp;
    const int row = blockIdx.x;
    const int tid = threadIdx.x;
    const size_t base = (size_t)row * D;
    float x[VPT];
    if (IN_RAW && !f32) {
        const bf16u* in = (const bf16u*)in_;
        #pragma unroll
        for (int i = 0; i < VPT; ++i) x[i] = bf2f(in[base + tid + i * 256]);
    } else {
        const float* in = (const float*)in_;
        #pragma unroll
        for (int i = 0; i < VPT; ++i) x[i] = in[base + tid + i * 256];
    }
    float s = 0.f, q = 0.f;
    #pragma unroll
    for (int i = 0; i < VPT; ++i) { s += x[i]; q += x[i] * x[i]; }
    __shared__ float red[10];
    #pragma unroll
    for (int off = 32; off; off >>= 1) {
        s += __shfl_down(s, off, 64);
        q += __shfl_down(q, off, 64);
    }
    const int lane = tid & 63, wv = tid >> 6;
    if (lane == 0) { red[wv] = s; red[4 + wv] = q; }
    __syncthreads();
    if (tid == 0) {
        float ts = red[0] + red[1] + red[2] + red[3];
        float tq = red[4] + red[5] + red[6] + red[7];
        float mean = ts / (float)D;
        float var = tq / (float)D - mean * mean;
        red[8] = mean;
        red[9] = rsqrtf(var + 1e-5f);
    }
    __syncthreads();
    const float mean = red[8], rstd = red[9];
    #pragma unroll
    for (int i = 0; i < VPT; ++i) {
        const int c = tid + i * 256;
        float gv, bv;
        if (f32) {
            gv = ((const float*)gvec)[c];
            bv = ((const float*)bvec)[c];
        } else {
            gv = bf2f(((const bf16u*)gvec)[c]);
            bv = bf2f(((const bf16u*)bvec)[c]);
        }
        float v = (x[i] - mean) * rstd * gv + bv;
        if (SILU) v *= sigmoidf_(v);
        if (OUT_RAW) {
            if (f32) ((float*)out_)[base + c] = v;
            else     ((bf16u*)out_)[base + c] = f2bf(v);
        } else {
            ((float*)out_)[base + c] = v;
        }
        if (COPY) copy_out[base + c] = x[i];
    }
}

// ---------- generic GEMM: C = res + alpha * act(A @ W + bias) ----------
__global__ __launch_bounds__(256) void gemm_kernel(
    const float* __restrict__ A, const void* __restrict__ W,
    const void* __restrict__ bias, const float* __restrict__ res,
    float* __restrict__ C, int M, int N, int K, float alpha, int act,
    const int* __restrict__ flagp)
{
    __shared__ float As[16][64];
    __shared__ float Bs[16][64];
    const int f32 = *flagp;
    const int tid = threadIdx.x;
    const int bm = blockIdx.y * 64, bn = blockIdx.x * 64;
    const int tx = tid & 15, ty = tid >> 4;
    const int arow = tid >> 2, acol = (tid & 3) * 4;
    const int brow = tid >> 4, bcol = (tid & 15) * 4;
    const float* aptr = A + (size_t)(bm + arow) * K + acol;
    float acc[4][4] = {};
    for (int k0 = 0; k0 < K; k0 += 16) {
        float4 av = *(const float4*)(aptr + k0);
        const size_t widx = (size_t)(brow + k0) * N + bn + bcol;
        float4 bfv;
        if (f32) {
            bfv = *(const float4*)((const float*)W + widx);
        } else {
            ushort4 bv = *(const ushort4*)((const bf16u*)W + widx);
            bfv.x = bf2f(bv.x); bfv.y = bf2f(bv.y);
            bfv.z = bf2f(bv.z); bfv.w = bf2f(bv.w);
        }
        __syncthreads();
        As[acol + 0][arow] = av.x;
        As[acol + 1][arow] = av.y;
        As[acol + 2][arow] = av.z;
        As[acol + 3][arow] = av.w;
        *(float4*)&Bs[brow][bcol] = bfv;
        __syncthreads();
        #pragma unroll
        for (int kk = 0; kk < 16; ++kk) {
            float4 a4 = *(const float4*)&As[kk][ty * 4];
            float4 b4 = *(const float4*)&Bs[kk][tx * 4];
            float ar[4] = {a4.x, a4.y, a4.z, a4.w};
            float br[4] = {b4.x, b4.y, b4.z, b4.w};
            #pragma unroll
            for (int i = 0; i < 4; ++i)
                #pragma unroll
                for (int j = 0; j < 4; ++j)
                    acc[i][j] = fmaf(ar[i], br[j], acc[i][j]);
        }
    }
    float bias4[4] = {0.f, 0.f, 0.f, 0.f};
    if (bias) {
        if (f32) {
            #pragma unroll
            for (int j = 0; j < 4; ++j) bias4[j] = ((const float*)bias)[bn + tx * 4 + j];
        } else {
            #pragma unroll
            for (int j = 0; j < 4; ++j) bias4[j] = bf2f(((const bf16u*)bias)[bn + tx * 4 + j]);
        }
    }
    #pragma unroll
    for (int i = 0; i < 4; ++i) {
        const int m = bm + ty * 4 + i;
        const size_t off = (size_t)m * N + bn + tx * 4;
        float v[4];
        #pragma unroll
        for (int j = 0; j < 4; ++j) {
            float t = acc[i][j] + bias4[j];
            if (act == 1) t *= sigmoidf_(t);
            v[j] = t * alpha;
        }
        if (res) {
            float4 r4 = *(const float4*)(res + off);
            v[0] += r4.x; v[1] += r4.y; v[2] += r4.z; v[3] += r4.w;
        }
        float4 o4 = {v[0], v[1], v[2], v[3]};
        *(float4*)(C + off) = o4;
    }
}

// ---------- attention NT gemm: C[h][i][j] = sum_d (A[i,h*64+d]+bias[h*64+d]) * B[j,h*64+d] ----------
// A,B: [1024, 512] fp32. C: [8][1024][1024]. Grid (16 j, 16 i, 8 h).
__global__ __launch_bounds__(256) void attn_nt_gemm(
    const float* __restrict__ A, const void* __restrict__ bias,
    const float* __restrict__ B, float* __restrict__ C,
    const int* __restrict__ flagp)
{
    __shared__ float As[16][64];
    __shared__ float Bs[16][64];
    const int f32 = *flagp;
    const int tid = threadIdx.x;
    const int bj = blockIdx.x * 64, bi = blockIdx.y * 64;
    const int hoff = blockIdx.z * 64;
    const int tx = tid & 15, ty = tid >> 4;
    const int arow = tid >> 2, acol = (tid & 3) * 4;
    float acc[4][4] = {};
    for (int d0 = 0; d0 < 64; d0 += 16) {
        float4 av = *(const float4*)(A + (size_t)(bi + arow) * 512 + hoff + d0 + acol);
        float4 bv = *(const float4*)(B + (size_t)(bj + arow) * 512 + hoff + d0 + acol);
        float4 b4;
        if (f32) {
            b4 = *(const float4*)((const float*)bias + hoff + d0 + acol);
        } else {
            ushort4 bb = *(const ushort4*)((const bf16u*)bias + hoff + d0 + acol);
            b4.x = bf2f(bb.x); b4.y = bf2f(bb.y); b4.z = bf2f(bb.z); b4.w = bf2f(bb.w);
        }
        av.x += b4.x; av.y += b4.y; av.z += b4.z; av.w += b4.w;
        __syncthreads();
        As[acol + 0][arow] = av.x;
        As[acol + 1][arow] = av.y;
        As[acol + 2][arow] = av.z;
        As[acol + 3][arow] = av.w;
        Bs[acol + 0][arow] = bv.x;
        Bs[acol + 1][arow] = bv.y;
        Bs[acol + 2][arow] = bv.z;
        Bs[acol + 3][arow] = bv.w;
        __syncthreads();
        #pragma unroll
        for (int kk = 0; kk < 16; ++kk) {
            float4 a4 = *(const float4*)&As[kk][ty * 4];
            float4 bq = *(const float4*)&Bs[kk][tx * 4];
            float ar[4] = {a4.x, a4.y, a4.z, a4.w};
            float br[4] = {bq.x, bq.y, bq.z, bq.w};
            #pragma unroll
            for (int i = 0; i < 4; ++i)
                #pragma unroll
                for (int j = 0; j < 4; ++j)
                    acc[i][j] = fmaf(ar[i], br[j], acc[i][j]);
        }
    }
    float* Cp = C + (size_t)blockIdx.z * 1048576;
    #pragma unroll
    for (int i = 0; i < 4; ++i) {
        float4 o4 = {acc[i][0], acc[i][1], acc[i][2], acc[i][3]};
        *(float4*)(Cp + (size_t)(bi + ty * 4 + i) * 1024 + bj + tx * 4) = o4;
    }
}

// ---------- softmax with rel-shift gather ----------
// Grid (1024 i, 8 h), 256 thr. In-place on S rows; BD is the raw q_v@P^T.
// rel_shift: j<=i -> BD[i, 1023-i+j]; j==i+1 -> 0; j>=i+2 -> BD[i+1, j-i-2].
__global__ __launch_bounds__(256) void attn_softmax_kernel(
    float* __restrict__ S, const float* __restrict__ BD)
{
    const int i = blockIdx.x, h = blockIdx.y;
    const int tid = threadIdx.x;
    float* srow = S + (size_t)h * 1048576 + (size_t)i * 1024;
    const float* bd0 = BD + (size_t)h * 1048576 + (size_t)i * 1024;
    const float* bd1 = bd0 + 1024;
    float v[4];
    #pragma unroll
    for (int k = 0; k < 4; ++k) {
        const int j = tid + k * 256;
        float bd;
        if (j <= i)          bd = bd0[1023 - i + j];
        else if (j == i + 1) bd = 0.f;
        else                 bd = bd1[j - i - 2];
        v[k] = (srow[j] + bd) * 0.125f;
    }
    __shared__ float red[6];
    float m = fmaxf(fmaxf(v[0], v[1]), fmaxf(v[2], v[3]));
    #pragma unroll
    for (int off = 32; off; off >>= 1) m = fmaxf(m, __shfl_down(m, off, 64));
    const int lane = tid & 63, w = tid >> 6;
    if (lane == 0) red[w] = m;
    __syncthreads();
    if (tid == 0) red[4] = fmaxf(fmaxf(red[0], red[1]), fmaxf(red[2], red[3]));
    __syncthreads();
    m = red[4];
    float e[4], l = 0.f;
    #pragma unroll
    for (int k = 0; k < 4; ++k) { e[k] = __expf(v[k] - m); l += e[k]; }
    #pragma unroll
    for (int off = 32; off; off >>= 1) l += __shfl_down(l, off, 64);
    if (lane == 0) red[w] = l;
    __syncthreads();
    if (tid == 0) red[5] = red[0] + red[1] + red[2] + red[3];
    __syncthreads();
    const float inv = 1.0f / red[5];
    #pragma unroll
    for (int k = 0; k < 4; ++k) srow[tid + k * 256] = e[k] * inv;
}

// ---------- attention PV gemm: O[i, h*64+n] = sum_j S[h][i][j] * V[j, h*64+n] ----------
// Grid (32 i-tiles, 8 h), 256 thr, 32x64 tile, 2x4 micro.
__global__ __launch_bounds__(256) void attn_pv_gemm(
    const float* __restrict__ S, const float* __restrict__ V,
    float* __restrict__ O)
{
    __shared__ float As[16][32];
    __shared__ float Bs[16][64];
    const int tid = threadIdx.x;
    const int bi = blockIdx.x * 32;
    const int hoff = blockIdx.y * 64;
    const int tx = tid & 15, ty = tid >> 4;           // ty: 0..15 -> i pairs
    const int arow = tid >> 3, acol = (tid & 7) * 2;  // A tile: 32 i x 16 k
    const int brow = tid >> 4, bcol = (tid & 15) * 4; // B tile: 16 k x 64 n
    const float* Ap = S + (size_t)blockIdx.y * 1048576;
    float acc[2][4] = {};
    for (int k0 = 0; k0 < 1024; k0 += 16) {
        float2 av = *(const float2*)(Ap + (size_t)(bi + arow) * 1024 + k0 + acol);
        float4 bv = *(const float4*)(V + (size_t)(k0 + brow) * 512 + hoff + bcol);
        __syncthreads();
        As[acol + 0][arow] = av.x;
        As[acol + 1][arow] = av.y;
        *(float4*)&Bs[brow][bcol] = bv;
        __syncthreads();
        #pragma unroll
        for (int kk = 0; kk < 16; ++kk) {
            float2 a2 = *(const float2*)&As[kk][ty * 2];
            float4 b4 = *(const float4*)&Bs[kk][tx * 4];
            float ar[2] = {a2.x, a2.y};
            float br[4] = {b4.x, b4.y, b4.z, b4.w};
            #pragma unroll
            for (int i = 0; i < 2; ++i)
                #pragma unroll
                for (int j = 0; j < 4; ++j)
                    acc[i][j] = fmaf(ar[i], br[j], acc[i][j]);
        }
    }
    #pragma unroll
    for (int i = 0; i < 2; ++i) {
        float4 o4 = {acc[i][0], acc[i][1], acc[i][2], acc[i][3]};
        *(float4*)(O + (size_t)(bi + ty * 2 + i) * 512 + hoff + tx * 4) = o4;
    }
}

// ---------- GLU ----------
__global__ __launch_bounds__(256) void glu_kernel(
    const float* __restrict__ H, float* __restrict__ out, int total)
{
    const int idx = blockIdx.x * 256 + threadIdx.x;
    if (idx >= total) return;
    const int m = idx >> 10, c = idx & 1023;
    const float a = H[(size_t)m * 2048 + c];
    const float g = H[(size_t)m * 2048 + 1024 + c];
    out[idx] = a * sigmoidf_(g);
}

// ---------- depthwise conv, K=33, pad 16 ----------
__global__ __launch_bounds__(256) void dwconv_kernel(
    const float* __restrict__ in, const void* __restrict__ wp,
    float* __restrict__ out, const int* __restrict__ flagp)
{
    const int f32 = *flagp;
    const int m = blockIdx.x;          // b*T + t
    const int b = m >> 10, t = m & 1023;
    for (int c = threadIdx.x; c < 1024; c += 256) {
        float wloc[33];
        if (f32) {
            #pragma unroll
            for (int k = 0; k < 33; ++k) wloc[k] = ((const float*)wp)[c * 33 + k];
        } else {
            #pragma unroll
            for (int k = 0; k < 33; ++k) wloc[k] = bf2f(((const bf16u*)wp)[c * 33 + k]);
        }
        float acc = 0.f;
        #pragma unroll
        for (int k = 0; k < 33; ++k) {
            const int tt = t + k - 16;
            if (tt >= 0 && tt < 1024)
                acc = fmaf(in[((size_t)(b << 10) + tt) * 1024 + c], wloc[k], acc);
        }
        out[(size_t)m * 1024 + c] = acc;
    }
}

static inline void launch_gemm(const float* A, const void* W, const void* bias,
                               const float* res, float* C, int M, int N, int K,
                               float alpha, int act, const int* flagp,
                               hipStream_t stream)
{
    dim3 grid(N / 64, M / 64);
    gemm_kernel<<<grid, 256, 0, stream>>>(A, W, bias, res, C, M, N, K, alpha, act, flagp);
}

extern "C" void kernel_launch(void* const* d_in, const int* in_sizes, int n_in,
                              void* d_out, int out_size, void* d_ws, size_t ws_size,
                              hipStream_t stream)
{
    const void* x       = d_in[0];
    const void* pos_emb = d_in[1];
    const void* ln1_g   = d_in[2];
    const void* ln1_b   = d_in[3];
    const void* ffn1_w1 = d_in[4];
    const void* ffn1_b1 = d_in[5];
    const void* ffn1_w2 = d_in[6];
    const void* ffn1_b2 = d_in[7];
    const void* lnq_g   = d_in[8];
    const void* lnq_b   = d_in[9];
    const void* lnk_g   = d_in[10];
    const void* lnk_b   = d_in[11];
    const void* lnv_g   = d_in[12];
    const void* lnv_b   = d_in[13];
    const void* wq      = d_in[14];
    const void* wk      = d_in[15];
    const void* wv      = d_in[16];
    const void* wpos    = d_in[17];
    const void* pbu     = d_in[18];
    const void* pbv     = d_in[19];
    const void* wfc     = d_in[20];
    const void* cln_g   = d_in[21];
    const void* cln_b   = d_in[22];
    const void* pw1     = d_in[23];
    const void* dw_w    = d_in[24];
    const void* bn_g    = d_in[25];
    const void* bn_b    = d_in[26];
    const void* pw2     = d_in[27];
    const void* ln2_g   = d_in[28];
    const void* ln2_b   = d_in[29];
    const void* ffn2_w1 = d_in[30];
    const void* ffn2_b1 = d_in[31];
    const void* ffn2_w2 = d_in[32];
    const void* ffn2_b2 = d_in[33];
    const void* lnf_g   = d_in[34];
    const void* lnf_b   = d_in[35];

    const int BT = 8192;           // B*T rows
    float* ws = (float*)d_ws;
    float* act  = ws;              // [8192,512]
    float* tmp  = ws +  4194304;   // [8192,512]  LN outputs / attn out
    float* hbuf = ws +  8388608;   // [8192,2048] = 16.78M floats
    float* qb   = ws + 25165824;   // [8192,512]
    float* kb   = ws + 29360128;   // [8192,512]
    float* vb   = ws + 33554432;   // [8192,512]
    float* pb   = ws + 37748736;   // [1024,512]
    int*   flagp = (int*)(ws + 38273024);
    float* ob   = tmp;             // attn output reuses tmp
    float* S    = hbuf;            // [8,1024,1024] per-b scores
    float* BD   = hbuf + 8388608;  // [8,1024,1024] per-b raw bd
    float* glu  = qb;              // [8192,1024] spans qb..kb
    float* dwo  = hbuf;            // [8192,1024]

    // ---- dtype detection ----
    init_flag_kernel<<<1, 64, 0, stream>>>(flagp);
    detect_kernel<<<256, 256, 0, stream>>>(x, in_sizes[0], flagp);

    // ---- P = pos_emb @ wpos (tmp as fp32 staging) ----
    cvt_kernel<<<2048, 256, 0, stream>>>(pos_emb, tmp, 524288, flagp);
    launch_gemm(tmp, wpos, nullptr, nullptr, pb, 1024, 512, 512, 1.0f, 0, flagp, stream);

    // ---- FFN1 half-step: act = x + 0.5*ffn(x) ----
    ln_kernel<512, true, false, false, true><<<BT, 256, 0, stream>>>(x, ln1_g, ln1_b, tmp, act, flagp);
    launch_gemm(tmp, ffn1_w1, ffn1_b1, nullptr, hbuf, BT, 2048, 512, 1.0f, 1, flagp, stream);
    launch_gemm(hbuf, ffn1_w2, ffn1_b2, act, act, BT, 512, 2048, 0.5f, 0, flagp, stream);

    // ---- MHSA projections ----
    ln_kernel<512, false, false, false, false><<<BT, 256, 0, stream>>>(act, lnq_g, lnq_b, tmp, nullptr, flagp);
    launch_gemm(tmp, wq, nullptr, nullptr, qb, BT, 512, 512, 1.0f, 0, flagp, stream);
    ln_kernel<512, false, false, false, false><<<BT, 256, 0, stream>>>(act, lnk_g, lnk_b, tmp, nullptr, flagp);
    launch_gemm(tmp, wk, nullptr, nullptr, kb, BT, 512, 512, 1.0f, 0, flagp, stream);
    ln_kernel<512, false, false, false, false><<<BT, 256, 0, stream>>>(act, lnv_g, lnv_b, tmp, nullptr, flagp);
    launch_gemm(tmp, wv, nullptr, nullptr, vb, BT, 512, 512, 1.0f, 0, flagp, stream);

    // ---- attention, one batch at a time (S/BD fit in hbuf) ----
    for (int b = 0; b < 8; ++b) {
        const float* Qb = qb + (size_t)b * 524288;
        const float* Kb = kb + (size_t)b * 524288;
        const float* Vb = vb + (size_t)b * 524288;
        float* Ob = ob + (size_t)b * 524288;
        attn_nt_gemm<<<dim3(16, 16, 8), 256, 0, stream>>>(Qb, pbu, Kb, S, flagp);
        attn_nt_gemm<<<dim3(16, 16, 8), 256, 0, stream>>>(Qb, pbv, pb, BD, flagp);
        attn_softmax_kernel<<<dim3(1024, 8), 256, 0, stream>>>(S, BD);
        attn_pv_gemm<<<dim3(32, 8), 256, 0, stream>>>(S, Vb, Ob);
    }
    launch_gemm(ob, wfc, nullptr, act, act, BT, 512, 512, 1.0f, 0, flagp, stream);

    // ---- convolution module ----
    ln_kernel<512, false, false, false, false><<<BT, 256, 0, stream>>>(act, cln_g, cln_b, tmp, nullptr, flagp);
    launch_gemm(tmp, pw1, nullptr, nullptr, hbuf, BT, 2048, 512, 1.0f, 0, flagp, stream);
    glu_kernel<<<32768, 256, 0, stream>>>(hbuf, glu, 8388608);
    dwconv_kernel<<<BT, 256, 0, stream>>>(glu, dw_w, dwo, flagp);
    ln_kernel<1024, false, false, true, false><<<BT, 256, 0, stream>>>(dwo, bn_g, bn_b, glu, nullptr, flagp);
    launch_gemm(glu, pw2, nullptr, act, act, BT, 512, 1024, 1.0f, 0, flagp, stream);

    // ---- FFN2 half-step ----
    ln_kernel<512, false, false, false, false><<<BT, 256, 0, stream>>>(act, ln2_g, ln2_b, tmp, nullptr, flagp);
    launch_gemm(tmp, ffn2_w1, ffn2_b1, nullptr, hbuf, BT, 2048, 512, 1.0f, 1, flagp, stream);
    launch_gemm(hbuf, ffn2_w2, ffn2_b2, act, act, BT, 512, 2048, 0.5f, 0, flagp, stream);

    // ---- final LN -> out (dtype per flag) ----
    ln_kernel<512, false, true, false, false><<<BT, 256, 0, stream>>>(act, lnf_g, lnf_b, d_out, nullptr, flagp);
}

// Round 4
// 1742.379 us; speedup vs baseline: 3.5568x; 1.8124x over previous
//
#include <hip/hip_runtime.h>

// ---------- types / helpers ----------
typedef unsigned short bf16u;
typedef __attribute__((ext_vector_type(8))) short bf16x8;   // MFMA A/B frag (4 VGPR)
typedef __attribute__((ext_vector_type(4))) float f32x4;    // MFMA C/D frag

__device__ __forceinline__ float bf2f(bf16u u) {
    return __uint_as_float(((unsigned)u) << 16);
}
__device__ __forceinline__ bf16u f2bf(float f) {
    unsigned u = __float_as_uint(f);
    unsigned r = (u + 0x7fffu + ((u >> 16) & 1u)) >> 16;
    return (bf16u)r;
}
__device__ __forceinline__ float sigmoidf_(float x) {
    return 1.0f / (1.0f + __expf(-x));
}

// ---------- dtype detection (flag=1 -> raw inputs fp32, 0 -> bf16) ----------
__global__ void init_flag_kernel(int* flag) {
    if (threadIdx.x == 0 && blockIdx.x == 0) *flag = 0;
}
__global__ __launch_bounds__(256) void detect_kernel(
    const void* x, int nelem, int* flag)
{
    const int scan = nelem < (1 << 20) ? nelem : (1 << 20);
    const bf16u* p = (const bf16u*)x;
    int bad = 0;
    for (int j = blockIdx.x * 256 + threadIdx.x; j < scan; j += 65536) {
        unsigned u = p[j];
        if ((u & 0x7F80u) == 0x7F80u) bad = 1;
    }
    if (bad) atomicOr(flag, 1);
}

// ---------- convert raw (bf16/fp32 per flag) -> bf16 ----------
__global__ __launch_bounds__(256) void cvt_bf_kernel(
    const void* __restrict__ in, bf16u* __restrict__ out, int n,
    const int* __restrict__ flagp)
{
    const int f32 = *flagp;
    const int i = blockIdx.x * 256 + threadIdx.x;
    if (i >= n) return;
    if (f32) out[i] = f2bf(((const float*)in)[i]);
    else     out[i] = ((const bf16u*)in)[i];
}

// ---------- weight transpose+convert: W[K,N] raw -> Wt[N,K] bf16 ----------
__global__ __launch_bounds__(256) void wtrans_kernel(
    const void* __restrict__ W, bf16u* __restrict__ Wt, int K, int N,
    const int* __restrict__ flagp)
{
    __shared__ float tile[32][33];
    const int f32 = *flagp;
    const int n0 = blockIdx.x * 32, k0 = blockIdx.y * 32;
    const int tx = threadIdx.x & 31, ty = threadIdx.x >> 5;  // ty 0..7
    #pragma unroll
    for (int r = 0; r < 4; ++r) {
        const int k = ty + r * 8;
        float v;
        if (f32) v = ((const float*)W)[(size_t)(k0 + k) * N + n0 + tx];
        else     v = bf2f(((const bf16u*)W)[(size_t)(k0 + k) * N + n0 + tx]);
        tile[k][tx] = v;
    }
    __syncthreads();
    #pragma unroll
    for (int r = 0; r < 4; ++r) {
        const int n = ty + r * 8;
        Wt[(size_t)(n0 + n) * K + k0 + tx] = f2bf(tile[tx][n]);
    }
}

// ---------- LayerNorm ----------
// IN_MODE: 0=fp32 ws, 1=raw (flag dtype), 2=bf16 ws.
// OUT_MODE: 0=bf16 ws, 1=raw d_out (flag dtype).
template <int D, int IN_MODE, int OUT_MODE, bool SILU, bool COPY>
__global__ __launch_bounds__(256) void ln_kernel(
    const void* __restrict__ in_, const void* __restrict__ gvec,
    const void* __restrict__ bvec, void* __restrict__ out_,
    float* __restrict__ copy_out, const int* __restrict__ flagp)
{
    constexpr int VPT = D / 256;
    const int f32 = *flagp;
    const int row = blockIdx.x;
    const int tid = threadIdx.x;
    const size_t base = (size_t)row * D;
    float x[VPT];
    if (IN_MODE == 2 || (IN_MODE == 1 && !f32)) {
        const bf16u* in = (const bf16u*)in_;
        #pragma unroll
        for (int i = 0; i < VPT; ++i) x[i] = bf2f(in[base + tid + i * 256]);
    } else {
        const float* in = (const float*)in_;
        #pragma unroll
        for (int i = 0; i < VPT; ++i) x[i] = in[base + tid + i * 256];
    }
    float s = 0.f, q = 0.f;
    #pragma unroll
    for (int i = 0; i < VPT; ++i) { s += x[i]; q += x[i] * x[i]; }
    __shared__ float red[10];
    #pragma unroll
    for (int off = 32; off; off >>= 1) {
        s += __shfl_down(s, off, 64);
        q += __shfl_down(q, off, 64);
    }
    const int lane = tid & 63, wv = tid >> 6;
    if (lane == 0) { red[wv] = s; red[4 + wv] = q; }
    __syncthreads();
    if (tid == 0) {
        float ts = red[0] + red[1] + red[2] + red[3];
        float tq = red[4] + red[5] + red[6] + red[7];
        float mean = ts / (float)D;
        float var = tq / (float)D - mean * mean;
        red[8] = mean;
        red[9] = rsqrtf(var + 1e-5f);
    }
    __syncthreads();
    const float mean = red[8], rstd = red[9];
    #pragma unroll
    for (int i = 0; i < VPT; ++i) {
        const int c = tid + i * 256;
        float gv, bv;
        if (f32) {
            gv = ((const float*)gvec)[c];
            bv = ((const float*)bvec)[c];
        } else {
            gv = bf2f(((const bf16u*)gvec)[c]);
            bv = bf2f(((const bf16u*)bvec)[c]);
        }
        float v = (x[i] - mean) * rstd * gv + bv;
        if (SILU) v *= sigmoidf_(v);
        if (OUT_MODE == 0) {
            ((bf16u*)out_)[base + c] = f2bf(v);
        } else {
            if (f32) ((float*)out_)[base + c] = v;
            else     ((bf16u*)out_)[base + c] = f2bf(v);
        }
        if (COPY) copy_out[base + c] = x[i];
    }
}

// ---------- MFMA GEMM: C = res + alpha * act(A @ Wt^T + bias) ----------
// A bf16 [M,K] row-major (k-contiguous), Wt bf16 [N,K] row-major.
// bias raw [N] (flag dtype) or null; res fp32 [M,N] or null.
// C fp32 (outbf=0) or bf16 (outbf=1). act: 0=none, 1=silu.
// 128x128 tile, BK=32, 256 thr = 4 waves (2x2), each wave 4x4 of 16x16x32.
__global__ __launch_bounds__(256) void gemm_mfma(
    const bf16u* __restrict__ A, const bf16u* __restrict__ Wt,
    const void* __restrict__ bias, const float* __restrict__ res,
    void* __restrict__ C, int M, int N, int K, float alpha, int act,
    int outbf, const int* __restrict__ flagp)
{
    __shared__ bf16u As[128 * 32];
    __shared__ bf16u Bs[128 * 32];
    const int f32 = *flagp;
    const int tid = threadIdx.x;
    const int bm = blockIdx.y * 128, bn = blockIdx.x * 128;
    const int lane = tid & 63, wvid = tid >> 6;
    const int wm = (wvid >> 1) * 64, wn = (wvid & 1) * 64;
    const int r0 = tid >> 2;         // staging row 0..63
    const int c0 = tid & 3;          // 16B chunk within 64B row

    f32x4 acc[4][4];
    {
        f32x4 z = {0.f, 0.f, 0.f, 0.f};
        #pragma unroll
        for (int i = 0; i < 4; ++i)
            #pragma unroll
            for (int j = 0; j < 4; ++j) acc[i][j] = z;
    }

    const int kq = (lane >> 4) * 8;       // fragment k-offset
    const int fr = lane & 15;             // fragment row (m or n)

    for (int k0 = 0; k0 < K; k0 += 32) {
        uint4 a0 = *(const uint4*)(A + (size_t)(bm + r0) * K + k0 + c0 * 8);
        uint4 a1 = *(const uint4*)(A + (size_t)(bm + 64 + r0) * K + k0 + c0 * 8);
        uint4 b0 = *(const uint4*)(Wt + (size_t)(bn + r0) * K + k0 + c0 * 8);
        uint4 b1 = *(const uint4*)(Wt + (size_t)(bn + 64 + r0) * K + k0 + c0 * 8);
        __syncthreads();
        *(uint4*)&As[(size_t)r0 * 32 + c0 * 8] = a0;
        *(uint4*)&As[(size_t)(64 + r0) * 32 + c0 * 8] = a1;
        *(uint4*)&Bs[(size_t)r0 * 32 + c0 * 8] = b0;
        *(uint4*)&Bs[(size_t)(64 + r0) * 32 + c0 * 8] = b1;
        __syncthreads();
        bf16x8 af[4], bfr[4];
        #pragma unroll
        for (int i = 0; i < 4; ++i)
            af[i] = *(const bf16x8*)&As[(size_t)(wm + i * 16 + fr) * 32 + kq];
        #pragma unroll
        for (int j = 0; j < 4; ++j)
            bfr[j] = *(const bf16x8*)&Bs[(size_t)(wn + j * 16 + fr) * 32 + kq];
        #pragma unroll
        for (int i = 0; i < 4; ++i)
            #pragma unroll
            for (int j = 0; j < 4; ++j)
                acc[i][j] = __builtin_amdgcn_mfma_f32_16x16x32_bf16(
                    af[i], bfr[j], acc[i][j], 0, 0, 0);
    }

    // epilogue: C/D layout col=lane&15 (n), row=quad*4+reg (m)
    const int quad = lane >> 4, col = lane & 15;
    #pragma unroll
    for (int j = 0; j < 4; ++j) {
        const int n = bn + wn + j * 16 + col;
        float bv = 0.f;
        if (bias) bv = f32 ? ((const float*)bias)[n]
                           : bf2f(((const bf16u*)bias)[n]);
        #pragma unroll
        for (int i = 0; i < 4; ++i) {
            #pragma unroll
            for (int r = 0; r < 4; ++r) {
                const int m = bm + wm + i * 16 + quad * 4 + r;
                float v = acc[i][j][r] + bv;
                if (act == 1) v *= sigmoidf_(v);
                v *= alpha;
                const size_t off = (size_t)m * N + n;
                if (res) v += res[off];
                if (outbf) ((bf16u*)C)[off] = f2bf(v);
                else       ((float*)C)[off] = v;
            }
        }
    }
}

// ---------- attention NT gemm (bf16 inputs, fp32 out) ----------
// C[h][i][j] = sum_d (A[i,h*64+d]+bias[h*64+d]) * B[j,h*64+d]
// A,B: bf16 [1024,512]. C: fp32 [8][1024][1024]. Grid (16 j, 16 i, 8 h).
__global__ __launch_bounds__(256) void attn_nt_gemm(
    const bf16u* __restrict__ A, const void* __restrict__ bias,
    const bf16u* __restrict__ B, float* __restrict__ C,
    const int* __restrict__ flagp)
{
    __shared__ float As[16][64];
    __shared__ float Bs[16][64];
    const int f32 = *flagp;
    const int tid = threadIdx.x;
    const int bj = blockIdx.x * 64, bi = blockIdx.y * 64;
    const int hoff = blockIdx.z * 64;
    const int tx = tid & 15, ty = tid >> 4;
    const int arow = tid >> 2, acol = (tid & 3) * 4;
    float acc[4][4] = {};
    for (int d0 = 0; d0 < 64; d0 += 16) {
        ushort4 au = *(const ushort4*)(A + (size_t)(bi + arow) * 512 + hoff + d0 + acol);
        ushort4 bu = *(const ushort4*)(B + (size_t)(bj + arow) * 512 + hoff + d0 + acol);
        float4 av = {bf2f(au.x), bf2f(au.y), bf2f(au.z), bf2f(au.w)};
        float4 bv = {bf2f(bu.x), bf2f(bu.y), bf2f(bu.z), bf2f(bu.w)};
        float4 b4;
        if (f32) {
            b4 = *(const float4*)((const float*)bias + hoff + d0 + acol);
        } else {
            ushort4 bb = *(const ushort4*)((const bf16u*)bias + hoff + d0 + acol);
            b4.x = bf2f(bb.x); b4.y = bf2f(bb.y); b4.z = bf2f(bb.z); b4.w = bf2f(bb.w);
        }
        av.x += b4.x; av.y += b4.y; av.z += b4.z; av.w += b4.w;
        __syncthreads();
        As[acol + 0][arow] = av.x;
        As[acol + 1][arow] = av.y;
        As[acol + 2][arow] = av.z;
        As[acol + 3][arow] = av.w;
        Bs[acol + 0][arow] = bv.x;
        Bs[acol + 1][arow] = bv.y;
        Bs[acol + 2][arow] = bv.z;
        Bs[acol + 3][arow] = bv.w;
        __syncthreads();
        #pragma unroll
        for (int kk = 0; kk < 16; ++kk) {
            float4 a4 = *(const float4*)&As[kk][ty * 4];
            float4 bq = *(const float4*)&Bs[kk][tx * 4];
            float ar[4] = {a4.x, a4.y, a4.z, a4.w};
            float br[4] = {bq.x, bq.y, bq.z, bq.w};
            #pragma unroll
            for (int i = 0; i < 4; ++i)
                #pragma unroll
                for (int j = 0; j < 4; ++j)
                    acc[i][j] = fmaf(ar[i], br[j], acc[i][j]);
        }
    }
    float* Cp = C + (size_t)blockIdx.z * 1048576;
    #pragma unroll
    for (int i = 0; i < 4; ++i) {
        float4 o4 = {acc[i][0], acc[i][1], acc[i][2], acc[i][3]};
        *(float4*)(Cp + (size_t)(bi + ty * 4 + i) * 1024 + bj + tx * 4) = o4;
    }
}

// ---------- softmax with rel-shift gather (fp32 S/BD, in-place) ----------
__global__ __launch_bounds__(256) void attn_softmax_kernel(
    float* __restrict__ S, const float* __restrict__ BD)
{
    const int i = blockIdx.x, h = blockIdx.y;
    const int tid = threadIdx.x;
    float* srow = S + (size_t)h * 1048576 + (size_t)i * 1024;
    const float* bd0 = BD + (size_t)h * 1048576 + (size_t)i * 1024;
    const float* bd1 = bd0 + 1024;
    float v[4];
    #pragma unroll
    for (int k = 0; k < 4; ++k) {
        const int j = tid + k * 256;
        float bd;
        if (j <= i)          bd = bd0[1023 - i + j];
        else if (j == i + 1) bd = 0.f;
        else                 bd = bd1[j - i - 2];
        v[k] = (srow[j] + bd) * 0.125f;
    }
    __shared__ float red[6];
    float m = fmaxf(fmaxf(v[0], v[1]), fmaxf(v[2], v[3]));
    #pragma unroll
    for (int off = 32; off; off >>= 1) m = fmaxf(m, __shfl_down(m, off, 64));
    const int lane = tid & 63, w = tid >> 6;
    if (lane == 0) red[w] = m;
    __syncthreads();
    if (tid == 0) red[4] = fmaxf(fmaxf(red[0], red[1]), fmaxf(red[2], red[3]));
    __syncthreads();
    m = red[4];
    float e[4], l = 0.f;
    #pragma unroll
    for (int k = 0; k < 4; ++k) { e[k] = __expf(v[k] - m); l += e[k]; }
    #pragma unroll
    for (int off = 32; off; off >>= 1) l += __shfl_down(l, off, 64);
    if (lane == 0) red[w] = l;
    __syncthreads();
    if (tid == 0) red[5] = red[0] + red[1] + red[2] + red[3];
    __syncthreads();
    const float inv = 1.0f / red[5];
    #pragma unroll
    for (int k = 0; k < 4; ++k) srow[tid + k * 256] = e[k] * inv;
}

// ---------- attention PV gemm: S fp32 @ V bf16 -> O bf16 ----------
// Grid (32 i-tiles, 8 h), 256 thr, 32x64 tile, 2x4 micro.
__global__ __launch_bounds__(256) void attn_pv_gemm(
    const float* __restrict__ S, const bf16u* __restrict__ V,
    bf16u* __restrict__ O)
{
    __shared__ float As[16][32];
    __shared__ float Bs[16][64];
    const int tid = threadIdx.x;
    const int bi = blockIdx.x * 32;
    const int hoff = blockIdx.y * 64;
    const int tx = tid & 15, ty = tid >> 4;
    const int arow = tid >> 3, acol = (tid & 7) * 2;
    const int brow = tid >> 4, bcol = (tid & 15) * 4;
    const float* Ap = S + (size_t)blockIdx.y * 1048576;
    float acc[2][4] = {};
    for (int k0 = 0; k0 < 1024; k0 += 16) {
        float2 av = *(const float2*)(Ap + (size_t)(bi + arow) * 1024 + k0 + acol);
        ushort4 bu = *(const ushort4*)(V + (size_t)(k0 + brow) * 512 + hoff + bcol);
        float4 bv = {bf2f(bu.x), bf2f(bu.y), bf2f(bu.z), bf2f(bu.w)};
        __syncthreads();
        As[acol + 0][arow] = av.x;
        As[acol + 1][arow] = av.y;
        *(float4*)&Bs[brow][bcol] = bv;
        __syncthreads();
        #pragma unroll
        for (int kk = 0; kk < 16; ++kk) {
            float2 a2 = *(const float2*)&As[kk][ty * 2];
            float4 b4 = *(const float4*)&Bs[kk][tx * 4];
            float ar[2] = {a2.x, a2.y};
            float br[4] = {b4.x, b4.y, b4.z, b4.w};
            #pragma unroll
            for (int i = 0; i < 2; ++i)
                #pragma unroll
                for (int j = 0; j < 4; ++j)
                    acc[i][j] = fmaf(ar[i], br[j], acc[i][j]);
        }
    }
    #pragma unroll
    for (int i = 0; i < 2; ++i) {
        ushort4 o4;
        o4.x = f2bf(acc[i][0]); o4.y = f2bf(acc[i][1]);
        o4.z = f2bf(acc[i][2]); o4.w = f2bf(acc[i][3]);
        *(ushort4*)(O + (size_t)(bi + ty * 2 + i) * 512 + hoff + tx * 4) = o4;
    }
}

// ---------- GLU: H fp32 -> G bf16 ----------
__global__ __launch_bounds__(256) void glu_kernel(
    const float* __restrict__ H, bf16u* __restrict__ out, int total)
{
    const int idx = blockIdx.x * 256 + threadIdx.x;
    if (idx >= total) return;
    const int m = idx >> 10, c = idx & 1023;
    const float a = H[(size_t)m * 2048 + c];
    const float g = H[(size_t)m * 2048 + 1024 + c];
    out[idx] = f2bf(a * sigmoidf_(g));
}

// ---------- depthwise conv K=33, pad 16 (bf16 in/out) ----------
__global__ __launch_bounds__(256) void dwconv_kernel(
    const bf16u* __restrict__ in, const void* __restrict__ wp,
    bf16u* __restrict__ out, const int* __restrict__ flagp)
{
    const int f32 = *flagp;
    const int m = blockIdx.x;          // b*T + t
    const int b = m >> 10, t = m & 1023;
    for (int c = threadIdx.x; c < 1024; c += 256) {
        float wloc[33];
        if (f32) {
            #pragma unroll
            for (int k = 0; k < 33; ++k) wloc[k] = ((const float*)wp)[c * 33 + k];
        } else {
            #pragma unroll
            for (int k = 0; k < 33; ++k) wloc[k] = bf2f(((const bf16u*)wp)[c * 33 + k]);
        }
        float acc = 0.f;
        #pragma unroll
        for (int k = 0; k < 33; ++k) {
            const int tt = t + k - 16;
            if (tt >= 0 && tt < 1024)
                acc = fmaf(bf2f(in[((size_t)(b << 10) + tt) * 1024 + c]), wloc[k], acc);
        }
        out[(size_t)m * 1024 + c] = f2bf(acc);
    }
}

static inline void launch_gemm(const bf16u* A, const bf16u* Wt, const void* bias,
                               const float* res, void* C, int M, int N, int K,
                               float alpha, int act, int outbf, const int* flagp,
                               hipStream_t stream)
{
    dim3 grid(N / 128, M / 128);
    gemm_mfma<<<grid, 256, 0, stream>>>(A, Wt, bias, res, C, M, N, K, alpha, act, outbf, flagp);
}

extern "C" void kernel_launch(void* const* d_in, const int* in_sizes, int n_in,
                              void* d_out, int out_size, void* d_ws, size_t ws_size,
                              hipStream_t stream)
{
    const void* x       = d_in[0];
    const void* pos_emb = d_in[1];
    const void* ln1_g   = d_in[2];
    const void* ln1_b   = d_in[3];
    const void* ffn1_w1 = d_in[4];
    const void* ffn1_b1 = d_in[5];
    const void* ffn1_w2 = d_in[6];
    const void* ffn1_b2 = d_in[7];
    const void* lnq_g   = d_in[8];
    const void* lnq_b   = d_in[9];
    const void* lnk_g   = d_in[10];
    const void* lnk_b   = d_in[11];
    const void* lnv_g   = d_in[12];
    const void* lnv_b   = d_in[13];
    const void* wq      = d_in[14];
    const void* wk      = d_in[15];
    const void* wv      = d_in[16];
    const void* wpos    = d_in[17];
    const void* pbu     = d_in[18];
    const void* pbv     = d_in[19];
    const void* wfc     = d_in[20];
    const void* cln_g   = d_in[21];
    const void* cln_b   = d_in[22];
    const void* pw1     = d_in[23];
    const void* dw_w    = d_in[24];
    const void* bn_g    = d_in[25];
    const void* bn_b    = d_in[26];
    const void* pw2     = d_in[27];
    const void* ln2_g   = d_in[28];
    const void* ln2_b   = d_in[29];
    const void* ffn2_w1 = d_in[30];
    const void* ffn2_b1 = d_in[31];
    const void* ffn2_w2 = d_in[32];
    const void* ffn2_b2 = d_in[33];
    const void* lnf_g   = d_in[34];
    const void* lnf_b   = d_in[35];

    const int BT = 8192;
    char* wsb = (char*)d_ws;
    // fp32 buffers
    float* act  = (float*)(wsb + 0);              // [8192,512] 16MB
    // bf16 buffers
    bf16u* qb   = (bf16u*)(wsb + 16777216);       // [8192,512] 8MB
    bf16u* kb   = (bf16u*)(wsb + 25165824);       // 8MB
    bf16u* vb   = (bf16u*)(wsb + 33554432);       // 8MB
    bf16u* pb   = (bf16u*)(wsb + 41943040);       // [1024,512] 1MB
    float* S    = (float*)(wsb + 42991616);       // [8,1024,1024] 32MB
    float* BD   = (float*)(wsb + 76546048);       // 32MB
    float* Hf   = (float*)(wsb + 42991616);       // [8192,2048] fp32 64MB (conv)
    bf16u* hbf  = (bf16u*)(wsb + 76546048);       // [8192,2048] bf16 32MB (FFN)
    bf16u* Gbf  = (bf16u*)(wsb + 16777216);       // [8192,1024] 16MB (conv, over q/k)
    bf16u* DWbf = (bf16u*)(wsb + 33554432);       // 16MB (conv, over v/pb/S-head)
    bf16u* LObf = (bf16u*)(wsb + 50331648);       // 16MB (conv ln out)
    bf16u* tmpb = (bf16u*)(wsb + 110100480);      // [8192,512] 8MB (LN out / pos / ob)
    bf16u* obb  = tmpb;                           // attn out (sequenced alias)
    bf16u* wc   = (bf16u*)(wsb + 118489088);      // weight cache 13.5MB
    int* flagp  = (int*)(wsb + 132644864);

    // weight cache offsets (bf16 elements)
    bf16u* w_ffn1_1 = wc + 0;        // [2048,512]
    bf16u* w_ffn1_2 = wc + 1048576;  // [512,2048]
    bf16u* w_q      = wc + 2097152;  // [512,512]
    bf16u* w_k      = wc + 2359296;
    bf16u* w_v      = wc + 2621440;
    bf16u* w_pos    = wc + 2883584;
    bf16u* w_fc     = wc + 3145728;
    bf16u* w_pw1    = wc + 3407872;  // [2048,512]
    bf16u* w_pw2    = wc + 4456448;  // [512,1024]
    bf16u* w_ffn2_1 = wc + 4980736;  // [2048,512]
    bf16u* w_ffn2_2 = wc + 6029312;  // [512,2048]

    // ---- dtype detection ----
    init_flag_kernel<<<1, 64, 0, stream>>>(flagp);
    detect_kernel<<<256, 256, 0, stream>>>(x, in_sizes[0], flagp);

    // ---- build transposed bf16 weight cache ----
    wtrans_kernel<<<dim3(64, 16), 256, 0, stream>>>(ffn1_w1, w_ffn1_1, 512, 2048, flagp);
    wtrans_kernel<<<dim3(16, 64), 256, 0, stream>>>(ffn1_w2, w_ffn1_2, 2048, 512, flagp);
    wtrans_kernel<<<dim3(16, 16), 256, 0, stream>>>(wq, w_q, 512, 512, flagp);
    wtrans_kernel<<<dim3(16, 16), 256, 0, stream>>>(wk, w_k, 512, 512, flagp);
    wtrans_kernel<<<dim3(16, 16), 256, 0, stream>>>(wv, w_v, 512, 512, flagp);
    wtrans_kernel<<<dim3(16, 16), 256, 0, stream>>>(wpos, w_pos, 512, 512, flagp);
    wtrans_kernel<<<dim3(16, 16), 256, 0, stream>>>(wfc, w_fc, 512, 512, flagp);
    wtrans_kernel<<<dim3(64, 16), 256, 0, stream>>>(pw1, w_pw1, 512, 2048, flagp);
    wtrans_kernel<<<dim3(16, 32), 256, 0, stream>>>(pw2, w_pw2, 1024, 512, flagp);
    wtrans_kernel<<<dim3(64, 16), 256, 0, stream>>>(ffn2_w1, w_ffn2_1, 512, 2048, flagp);
    wtrans_kernel<<<dim3(16, 64), 256, 0, stream>>>(ffn2_w2, w_ffn2_2, 2048, 512, flagp);

    // ---- P = pos_emb @ wpos -> pb bf16 ----
    cvt_bf_kernel<<<2048, 256, 0, stream>>>(pos_emb, tmpb, 524288, flagp);
    launch_gemm(tmpb, w_pos, nullptr, nullptr, pb, 1024, 512, 512, 1.0f, 0, 1, flagp, stream);

    // ---- FFN1 half-step ----
    ln_kernel<512, 1, 0, false, true><<<BT, 256, 0, stream>>>(x, ln1_g, ln1_b, tmpb, act, flagp);
    launch_gemm(tmpb, w_ffn1_1, ffn1_b1, nullptr, hbf, BT, 2048, 512, 1.0f, 1, 1, flagp, stream);
    launch_gemm(hbf, w_ffn1_2, ffn1_b2, act, act, BT, 512, 2048, 0.5f, 0, 0, flagp, stream);

    // ---- MHSA projections ----
    ln_kernel<512, 0, 0, false, false><<<BT, 256, 0, stream>>>(act, lnq_g, lnq_b, tmpb, nullptr, flagp);
    launch_gemm(tmpb, w_q, nullptr, nullptr, qb, BT, 512, 512, 1.0f, 0, 1, flagp, stream);
    ln_kernel<512, 0, 0, false, false><<<BT, 256, 0, stream>>>(act, lnk_g, lnk_b, tmpb, nullptr, flagp);
    launch_gemm(tmpb, w_k, nullptr, nullptr, kb, BT, 512, 512, 1.0f, 0, 1, flagp, stream);
    ln_kernel<512, 0, 0, false, false><<<BT, 256, 0, stream>>>(act, lnv_g, lnv_b, tmpb, nullptr, flagp);
    launch_gemm(tmpb, w_v, nullptr, nullptr, vb, BT, 512, 512, 1.0f, 0, 1, flagp, stream);

    // ---- attention per batch ----
    for (int b = 0; b < 8; ++b) {
        const bf16u* Qb = qb + (size_t)b * 524288;
        const bf16u* Kb = kb + (size_t)b * 524288;
        const bf16u* Vb = vb + (size_t)b * 524288;
        bf16u* Ob = obb + (size_t)b * 524288;
        attn_nt_gemm<<<dim3(16, 16, 8), 256, 0, stream>>>(Qb, pbu, Kb, S, flagp);
        attn_nt_gemm<<<dim3(16, 16, 8), 256, 0, stream>>>(Qb, pbv, pb, BD, flagp);
        attn_softmax_kernel<<<dim3(1024, 8), 256, 0, stream>>>(S, BD);
        attn_pv_gemm<<<dim3(32, 8), 256, 0, stream>>>(S, Vb, Ob);
    }
    launch_gemm(obb, w_fc, nullptr, act, act, BT, 512, 512, 1.0f, 0, 0, flagp, stream);

    // ---- convolution module ----
    ln_kernel<512, 0, 0, false, false><<<BT, 256, 0, stream>>>(act, cln_g, cln_b, tmpb, nullptr, flagp);
    launch_gemm(tmpb, w_pw1, nullptr, nullptr, Hf, BT, 2048, 512, 1.0f, 0, 0, flagp, stream);
    glu_kernel<<<32768, 256, 0, stream>>>(Hf, Gbf, 8388608);
    dwconv_kernel<<<BT, 256, 0, stream>>>(Gbf, dw_w, DWbf, flagp);
    ln_kernel<1024, 2, 0, true, false><<<BT, 256, 0, stream>>>(DWbf, bn_g, bn_b, LObf, nullptr, flagp);
    launch_gemm(LObf, w_pw2, nullptr, act, act, BT, 512, 1024, 1.0f, 0, 0, flagp, stream);

    // ---- FFN2 half-step ----
    ln_kernel<512, 0, 0, false, false><<<BT, 256, 0, stream>>>(act, ln2_g, ln2_b, tmpb, nullptr, flagp);
    launch_gemm(tmpb, w_ffn2_1, ffn2_b1, nullptr, hbf, BT, 2048, 512, 1.0f, 1, 1, flagp, stream);
    launch_gemm(hbf, w_ffn2_2, ffn2_b2, act, act, BT, 512, 2048, 0.5f, 0, 0, flagp, stream);

    // ---- final LN -> d_out ----
    ln_kernel<512, 0, 1, false, false><<<BT, 256, 0, stream>>>(act, lnf_g, lnf_b, d_out, nullptr, flagp);
}

// Round 5
// 1050.004 us; speedup vs baseline: 5.9021x; 1.6594x over previous
//
#include <hip/hip_runtime.h>

// ---------- types / helpers ----------
typedef unsigned short bf16u;
typedef __attribute__((ext_vector_type(8))) short bf16x8;   // MFMA A/B frag (4 VGPR)
typedef __attribute__((ext_vector_type(4))) float f32x4;    // MFMA C/D frag

__device__ __forceinline__ float bf2f(bf16u u) {
    return __uint_as_float(((unsigned)u) << 16);
}
__device__ __forceinline__ bf16u f2bf(float f) {
    unsigned u = __float_as_uint(f);
    unsigned r = (u + 0x7fffu + ((u >> 16) & 1u)) >> 16;
    return (bf16u)r;
}
__device__ __forceinline__ float sigmoidf_(float x) {
    return 1.0f / (1.0f + __expf(-x));
}

// ---------- dtype detection (flag=1 -> raw inputs fp32, 0 -> bf16) ----------
__global__ void init_flag_kernel(int* flag) {
    if (threadIdx.x == 0 && blockIdx.x == 0) *flag = 0;
}
__global__ __launch_bounds__(256) void detect_kernel(
    const void* x, int nelem, int* flag)
{
    const int scan = nelem < (1 << 20) ? nelem : (1 << 20);
    const bf16u* p = (const bf16u*)x;
    int bad = 0;
    for (int j = blockIdx.x * 256 + threadIdx.x; j < scan; j += 65536) {
        unsigned u = p[j];
        if ((u & 0x7F80u) == 0x7F80u) bad = 1;
    }
    if (bad) atomicOr(flag, 1);
}

// ---------- convert raw (bf16/fp32 per flag) -> bf16 ----------
__global__ __launch_bounds__(256) void cvt_bf_kernel(
    const void* __restrict__ in, bf16u* __restrict__ out, int n,
    const int* __restrict__ flagp)
{
    const int f32 = *flagp;
    const int i = blockIdx.x * 256 + threadIdx.x;
    if (i >= n) return;
    if (f32) out[i] = f2bf(((const float*)in)[i]);
    else     out[i] = ((const bf16u*)in)[i];
}

// ---------- weight transpose+convert: W[K,N] raw -> Wt[N,K] bf16 ----------
__global__ __launch_bounds__(256) void wtrans_kernel(
    const void* __restrict__ W, bf16u* __restrict__ Wt, int K, int N,
    const int* __restrict__ flagp)
{
    __shared__ float tile[32][33];
    const int f32 = *flagp;
    const int n0 = blockIdx.x * 32, k0 = blockIdx.y * 32;
    const int tx = threadIdx.x & 31, ty = threadIdx.x >> 5;  // ty 0..7
    #pragma unroll
    for (int r = 0; r < 4; ++r) {
        const int k = ty + r * 8;
        float v;
        if (f32) v = ((const float*)W)[(size_t)(k0 + k) * N + n0 + tx];
        else     v = bf2f(((const bf16u*)W)[(size_t)(k0 + k) * N + n0 + tx]);
        tile[k][tx] = v;
    }
    __syncthreads();
    #pragma unroll
    for (int r = 0; r < 4; ++r) {
        const int n = ty + r * 8;
        Wt[(size_t)(n0 + n) * K + k0 + tx] = f2bf(tile[tx][n]);
    }
}

// ---------- V transpose: vb [b*1024+j][512] -> vt [b][h][64 d][1024 j] ----------
__global__ __launch_bounds__(256) void vtrans_kernel(
    const bf16u* __restrict__ vb, bf16u* __restrict__ vt)
{
    __shared__ bf16u tile[32][33];
    const int j0 = blockIdx.x * 32;
    const int h = blockIdx.y >> 1, dt = (blockIdx.y & 1) * 32;
    const int b = blockIdx.z;
    const int tx = threadIdx.x & 31, ty = threadIdx.x >> 5;
    #pragma unroll
    for (int r = 0; r < 4; ++r) {
        const int j = ty + r * 8;
        tile[j][tx] = vb[(size_t)(b * 1024 + j0 + j) * 512 + h * 64 + dt + tx];
    }
    __syncthreads();
    #pragma unroll
    for (int r = 0; r < 4; ++r) {
        const int d = ty + r * 8;
        vt[(size_t)((b * 8 + h) * 64 + dt + d) * 1024 + j0 + tx] = tile[tx][d];
    }
}

// ---------- qu/qv = q + bias_u/v (bf16) ----------
__global__ __launch_bounds__(256) void add_qbias_kernel(
    const bf16u* __restrict__ qb, const void* __restrict__ bu,
    const void* __restrict__ bv, bf16u* __restrict__ qu,
    bf16u* __restrict__ qv, const int* __restrict__ flagp)
{
    const int f32 = *flagp;
    const int idx = blockIdx.x * 256 + threadIdx.x;
    const int c = idx & 511;
    const float q = bf2f(qb[idx]);
    float ub, vbias;
    if (f32) { ub = ((const float*)bu)[c]; vbias = ((const float*)bv)[c]; }
    else     { ub = bf2f(((const bf16u*)bu)[c]); vbias = bf2f(((const bf16u*)bv)[c]); }
    qu[idx] = f2bf(q + ub);
    qv[idx] = f2bf(q + vbias);
}

// ---------- LayerNorm ----------
// IN_MODE: 0=fp32 ws, 1=raw (flag dtype), 2=bf16 ws.
// OUT_MODE: 0=bf16 ws, 1=raw d_out (flag dtype).
template <int D, int IN_MODE, int OUT_MODE, bool SILU, bool COPY>
__global__ __launch_bounds__(256) void ln_kernel(
    const void* __restrict__ in_, const void* __restrict__ gvec,
    const void* __restrict__ bvec, void* __restrict__ out_,
    float* __restrict__ copy_out, const int* __restrict__ flagp)
{
    constexpr int VPT = D / 256;
    const int f32 = *flagp;
    const int row = blockIdx.x;
    const int tid = threadIdx.x;
    const size_t base = (size_t)row * D;
    float x[VPT];
    if (IN_MODE == 2 || (IN_MODE == 1 && !f32)) {
        const bf16u* in = (const bf16u*)in_;
        #pragma unroll
        for (int i = 0; i < VPT; ++i) x[i] = bf2f(in[base + tid + i * 256]);
    } else {
        const float* in = (const float*)in_;
        #pragma unroll
        for (int i = 0; i < VPT; ++i) x[i] = in[base + tid + i * 256];
    }
    float s = 0.f, q = 0.f;
    #pragma unroll
    for (int i = 0; i < VPT; ++i) { s += x[i]; q += x[i] * x[i]; }
    __shared__ float red[10];
    #pragma unroll
    for (int off = 32; off; off >>= 1) {
        s += __shfl_down(s, off, 64);
        q += __shfl_down(q, off, 64);
    }
    const int lane = tid & 63, wv = tid >> 6;
    if (lane == 0) { red[wv] = s; red[4 + wv] = q; }
    __syncthreads();
    if (tid == 0) {
        float ts = red[0] + red[1] + red[2] + red[3];
        float tq = red[4] + red[5] + red[6] + red[7];
        float mean = ts / (float)D;
        float var = tq / (float)D - mean * mean;
        red[8] = mean;
        red[9] = rsqrtf(var + 1e-5f);
    }
    __syncthreads();
    const float mean = red[8], rstd = red[9];
    #pragma unroll
    for (int i = 0; i < VPT; ++i) {
        const int c = tid + i * 256;
        float gv, bv;
        if (f32) {
            gv = ((const float*)gvec)[c];
            bv = ((const float*)bvec)[c];
        } else {
            gv = bf2f(((const bf16u*)gvec)[c]);
            bv = bf2f(((const bf16u*)bvec)[c]);
        }
        float v = (x[i] - mean) * rstd * gv + bv;
        if (SILU) v *= sigmoidf_(v);
        if (OUT_MODE == 0) {
            ((bf16u*)out_)[base + c] = f2bf(v);
        } else {
            if (f32) ((float*)out_)[base + c] = v;
            else     ((bf16u*)out_)[base + c] = f2bf(v);
        }
        if (COPY) copy_out[base + c] = x[i];
    }
}

// ---------- MFMA GEMM: C = res + alpha * act(A @ Wt^T + bias) ----------
__global__ __launch_bounds__(256) void gemm_mfma(
    const bf16u* __restrict__ A, const bf16u* __restrict__ Wt,
    const void* __restrict__ bias, const float* __restrict__ res,
    void* __restrict__ C, int M, int N, int K, float alpha, int act,
    int outbf, const int* __restrict__ flagp)
{
    __shared__ bf16u As[128 * 32];
    __shared__ bf16u Bs[128 * 32];
    const int f32 = *flagp;
    const int tid = threadIdx.x;
    const int bm = blockIdx.y * 128, bn = blockIdx.x * 128;
    const int lane = tid & 63, wvid = tid >> 6;
    const int wm = (wvid >> 1) * 64, wn = (wvid & 1) * 64;
    const int r0 = tid >> 2;
    const int c0 = tid & 3;

    f32x4 acc[4][4];
    {
        f32x4 z = {0.f, 0.f, 0.f, 0.f};
        #pragma unroll
        for (int i = 0; i < 4; ++i)
            #pragma unroll
            for (int j = 0; j < 4; ++j) acc[i][j] = z;
    }

    const int kq = (lane >> 4) * 8;
    const int fr = lane & 15;

    for (int k0 = 0; k0 < K; k0 += 32) {
        uint4 a0 = *(const uint4*)(A + (size_t)(bm + r0) * K + k0 + c0 * 8);
        uint4 a1 = *(const uint4*)(A + (size_t)(bm + 64 + r0) * K + k0 + c0 * 8);
        uint4 b0 = *(const uint4*)(Wt + (size_t)(bn + r0) * K + k0 + c0 * 8);
        uint4 b1 = *(const uint4*)(Wt + (size_t)(bn + 64 + r0) * K + k0 + c0 * 8);
        __syncthreads();
        *(uint4*)&As[(size_t)r0 * 32 + c0 * 8] = a0;
        *(uint4*)&As[(size_t)(64 + r0) * 32 + c0 * 8] = a1;
        *(uint4*)&Bs[(size_t)r0 * 32 + c0 * 8] = b0;
        *(uint4*)&Bs[(size_t)(64 + r0) * 32 + c0 * 8] = b1;
        __syncthreads();
        bf16x8 af[4], bfr[4];
        #pragma unroll
        for (int i = 0; i < 4; ++i)
            af[i] = *(const bf16x8*)&As[(size_t)(wm + i * 16 + fr) * 32 + kq];
        #pragma unroll
        for (int j = 0; j < 4; ++j)
            bfr[j] = *(const bf16x8*)&Bs[(size_t)(wn + j * 16 + fr) * 32 + kq];
        #pragma unroll
        for (int i = 0; i < 4; ++i)
            #pragma unroll
            for (int j = 0; j < 4; ++j)
                acc[i][j] = __builtin_amdgcn_mfma_f32_16x16x32_bf16(
                    af[i], bfr[j], acc[i][j], 0, 0, 0);
    }

    const int quad = lane >> 4, col = lane & 15;
    #pragma unroll
    for (int j = 0; j < 4; ++j) {
        const int n = bn + wn + j * 16 + col;
        float bv = 0.f;
        if (bias) bv = f32 ? ((const float*)bias)[n]
                           : bf2f(((const bf16u*)bias)[n]);
        #pragma unroll
        for (int i = 0; i < 4; ++i) {
            #pragma unroll
            for (int r = 0; r < 4; ++r) {
                const int m = bm + wm + i * 16 + quad * 4 + r;
                float v = acc[i][j][r] + bv;
                if (act == 1) v *= sigmoidf_(v);
                v *= alpha;
                const size_t off = (size_t)m * N + n;
                if (res) v += res[off];
                if (outbf) ((bf16u*)C)[off] = f2bf(v);
                else       ((float*)C)[off] = v;
            }
        }
    }
}

// ---------- attention score MFMA ----------
// grid (8 jt, 8 it, 16): z = which*8+h. which=0: S = (qu @ kb^T)*scale,
// which=1: BD = (qv @ pb^T)*scale. All operands bf16 [rows,512] d-contig.
__global__ __launch_bounds__(256) void attn_score_mfma(
    const bf16u* __restrict__ qu, const bf16u* __restrict__ qv,
    const bf16u* __restrict__ kb, const bf16u* __restrict__ pb,
    bf16u* __restrict__ S, bf16u* __restrict__ BD)
{
    __shared__ bf16u As[128 * 32];
    __shared__ bf16u Bs[128 * 32];
    const int tid = threadIdx.x;
    const int z = blockIdx.z;
    const int h = z & 7, which = z >> 3;
    const bf16u* A = which ? qv : qu;
    const bf16u* B = which ? pb : kb;
    bf16u* C = (which ? BD : S) + (size_t)h * 1048576;
    const int hoff = h * 64;
    const int bm = blockIdx.y * 128, bn = blockIdx.x * 128;
    const int lane = tid & 63, wvid = tid >> 6;
    const int wm = (wvid >> 1) * 64, wn = (wvid & 1) * 64;
    const int r0 = tid >> 2, c0 = tid & 3;
    f32x4 acc[4][4];
    {
        f32x4 zr = {0.f, 0.f, 0.f, 0.f};
        #pragma unroll
        for (int i = 0; i < 4; ++i)
            #pragma unroll
            for (int j = 0; j < 4; ++j) acc[i][j] = zr;
    }
    const int kq = (lane >> 4) * 8, fr = lane & 15;

    #pragma unroll
    for (int k0 = 0; k0 < 64; k0 += 32) {
        uint4 a0 = *(const uint4*)(A + (size_t)(bm + r0) * 512 + hoff + k0 + c0 * 8);
        uint4 a1 = *(const uint4*)(A + (size_t)(bm + 64 + r0) * 512 + hoff + k0 + c0 * 8);
        uint4 b0 = *(const uint4*)(B + (size_t)(bn + r0) * 512 + hoff + k0 + c0 * 8);
        uint4 b1 = *(const uint4*)(B + (size_t)(bn + 64 + r0) * 512 + hoff + k0 + c0 * 8);
        __syncthreads();
        *(uint4*)&As[(size_t)r0 * 32 + c0 * 8] = a0;
        *(uint4*)&As[(size_t)(64 + r0) * 32 + c0 * 8] = a1;
        *(uint4*)&Bs[(size_t)r0 * 32 + c0 * 8] = b0;
        *(uint4*)&Bs[(size_t)(64 + r0) * 32 + c0 * 8] = b1;
        __syncthreads();
        bf16x8 af[4], bfr[4];
        #pragma unroll
        for (int i = 0; i < 4; ++i)
            af[i] = *(const bf16x8*)&As[(size_t)(wm + i * 16 + fr) * 32 + kq];
        #pragma unroll
        for (int j = 0; j < 4; ++j)
            bfr[j] = *(const bf16x8*)&Bs[(size_t)(wn + j * 16 + fr) * 32 + kq];
        #pragma unroll
        for (int i = 0; i < 4; ++i)
            #pragma unroll
            for (int j = 0; j < 4; ++j)
                acc[i][j] = __builtin_amdgcn_mfma_f32_16x16x32_bf16(
                    af[i], bfr[j], acc[i][j], 0, 0, 0);
    }
    const int quad = lane >> 4, col = lane & 15;
    #pragma unroll
    for (int j = 0; j < 4; ++j) {
        const int n = bn + wn + j * 16 + col;
        #pragma unroll
        for (int i = 0; i < 4; ++i) {
            #pragma unroll
            for (int r = 0; r < 4; ++r) {
                const int m = bm + wm + i * 16 + quad * 4 + r;
                C[(size_t)m * 1024 + n] = f2bf(acc[i][j][r] * 0.125f);
            }
        }
    }
}

// ---------- softmax with rel-shift gather (bf16 S/BD, probs in-place) ----------
// rel_shift: j<=i -> BD[i,1023-i+j]; j==i+1 -> 0; j>=i+2 -> BD[i+1,j-i-2].
__global__ __launch_bounds__(256) void attn_softmax_kernel(
    bf16u* __restrict__ S, const bf16u* __restrict__ BD)
{
    const int i = blockIdx.x, h = blockIdx.y;
    const int tid = threadIdx.x;
    bf16u* srow = S + (size_t)h * 1048576 + (size_t)i * 1024;
    const bf16u* bd0 = BD + (size_t)h * 1048576 + (size_t)i * 1024;
    const bf16u* bd1 = bd0 + 1024;
    float v[4];
    #pragma unroll
    for (int k = 0; k < 4; ++k) {
        const int j = tid + k * 256;
        float bd;
        if (j <= i)          bd = bf2f(bd0[1023 - i + j]);
        else if (j == i + 1) bd = 0.f;
        else                 bd = bf2f(bd1[j - i - 2]);
        v[k] = bf2f(srow[j]) + bd;
    }
    __shared__ float red[6];
    float m = fmaxf(fmaxf(v[0], v[1]), fmaxf(v[2], v[3]));
    #pragma unroll
    for (int off = 32; off; off >>= 1) m = fmaxf(m, __shfl_down(m, off, 64));
    const int lane = tid & 63, w = tid >> 6;
    if (lane == 0) red[w] = m;
    __syncthreads();
    if (tid == 0) red[4] = fmaxf(fmaxf(red[0], red[1]), fmaxf(red[2], red[3]));
    __syncthreads();
    m = red[4];
    float e[4], l = 0.f;
    #pragma unroll
    for (int k = 0; k < 4; ++k) { e[k] = __expf(v[k] - m); l += e[k]; }
    #pragma unroll
    for (int off = 32; off; off >>= 1) l += __shfl_down(l, off, 64);
    if (lane == 0) red[w] = l;
    __syncthreads();
    if (tid == 0) red[5] = red[0] + red[1] + red[2] + red[3];
    __syncthreads();
    const float inv = 1.0f / red[5];
    #pragma unroll
    for (int k = 0; k < 4; ++k) srow[tid + k * 256] = f2bf(e[k] * inv);
}

// ---------- attention PV MFMA: O[i, h*64+d] = sum_j P[h][i][j] * Vt[h][d][j] ----------
// grid (16 i-tiles, 8 h). Tile M=64 i x N=64 d, K=1024 j.
__global__ __launch_bounds__(256) void attn_pv_mfma(
    const bf16u* __restrict__ P, const bf16u* __restrict__ Vt,
    bf16u* __restrict__ O)
{
    __shared__ bf16u As[64 * 32];
    __shared__ bf16u Bs[64 * 32];
    const int tid = threadIdx.x;
    const int h = blockIdx.y;
    const int bm = blockIdx.x * 64;
    const int hoff = h * 64;
    const bf16u* Ph = P + (size_t)h * 1048576;
    const bf16u* Vh = Vt + (size_t)h * 65536;
    const int lane = tid & 63, wvid = tid >> 6;
    const int wm = wvid * 16;
    const int r0 = tid >> 2, c0 = tid & 3;
    const int kq = (lane >> 4) * 8, fr = lane & 15;
    f32x4 acc[4];
    {
        f32x4 z = {0.f, 0.f, 0.f, 0.f};
        #pragma unroll
        for (int j = 0; j < 4; ++j) acc[j] = z;
    }
    for (int k0 = 0; k0 < 1024; k0 += 32) {
        uint4 a0 = *(const uint4*)(Ph + (size_t)(bm + r0) * 1024 + k0 + c0 * 8);
        uint4 b0 = *(const uint4*)(Vh + (size_t)r0 * 1024 + k0 + c0 * 8);
        __syncthreads();
        *(uint4*)&As[(size_t)r0 * 32 + c0 * 8] = a0;
        *(uint4*)&Bs[(size_t)r0 * 32 + c0 * 8] = b0;
        __syncthreads();
        bf16x8 af = *(const bf16x8*)&As[(size_t)(wm + fr) * 32 + kq];
        #pragma unroll
        for (int j = 0; j < 4; ++j) {
            bf16x8 bf = *(const bf16x8*)&Bs[(size_t)(j * 16 + fr) * 32 + kq];
            acc[j] = __builtin_amdgcn_mfma_f32_16x16x32_bf16(af, bf, acc[j], 0, 0, 0);
        }
    }
    const int quad = lane >> 4, col = lane & 15;
    #pragma unroll
    for (int j = 0; j < 4; ++j) {
        const int d = j * 16 + col;
        #pragma unroll
        for (int r = 0; r < 4; ++r) {
            const int m = bm + wm + quad * 4 + r;
            O[(size_t)m * 512 + hoff + d] = f2bf(acc[j][r]);
        }
    }
}

// ---------- GLU: H bf16 [m,2048] -> G bf16 [m,1024] ----------
__global__ __launch_bounds__(256) void glu_kernel(
    const bf16u* __restrict__ H, bf16u* __restrict__ out, int total)
{
    const int idx = blockIdx.x * 256 + threadIdx.x;
    if (idx >= total) return;
    const int m = idx >> 10, c = idx & 1023;
    const float a = bf2f(H[(size_t)m * 2048 + c]);
    const float g = bf2f(H[(size_t)m * 2048 + 1024 + c]);
    out[idx] = f2bf(a * sigmoidf_(g));
}

// ---------- depthwise conv K=33, pad 16, register sliding window ----------
// blockIdx.x = b*256 + ttile*2 + cb. Thread: channel-pair, 8 t outputs.
__global__ __launch_bounds__(256) void dwconv_kernel(
    const bf16u* __restrict__ in, const void* __restrict__ wp,
    bf16u* __restrict__ out, const int* __restrict__ flagp)
{
    const int f32 = *flagp;
    const int cb = blockIdx.x & 1;
    const int ttile = (blockIdx.x >> 1) & 127;
    const int b = blockIdx.x >> 8;
    const int t0 = ttile * 8;
    const int c = cb * 512 + threadIdx.x * 2;

    float w0[33], w1[33];
    if (f32) {
        const float* wf = (const float*)wp;
        #pragma unroll
        for (int k = 0; k < 33; ++k) { w0[k] = wf[c * 33 + k]; w1[k] = wf[(c + 1) * 33 + k]; }
    } else {
        const bf16u* wb = (const bf16u*)wp;
        #pragma unroll
        for (int k = 0; k < 33; ++k) { w0[k] = bf2f(wb[c * 33 + k]); w1[k] = bf2f(wb[(c + 1) * 33 + k]); }
    }

    unsigned win[40];
    #pragma unroll
    for (int r = 0; r < 40; ++r) {
        const int tt = t0 - 16 + r;
        win[r] = (tt >= 0 && tt < 1024)
               ? *(const unsigned*)(in + (size_t)(b * 1024 + tt) * 1024 + c)
               : 0u;
    }
    float acc0[8] = {}, acc1[8] = {};
    #pragma unroll
    for (int k = 0; k < 33; ++k) {
        #pragma unroll
        for (int dt = 0; dt < 8; ++dt) {
            const unsigned u = win[dt + k];
            acc0[dt] = fmaf(bf2f((bf16u)(u & 0xffffu)), w0[k], acc0[dt]);
            acc1[dt] = fmaf(bf2f((bf16u)(u >> 16)), w1[k], acc1[dt]);
        }
    }
    #pragma unroll
    for (int dt = 0; dt < 8; ++dt) {
        unsigned o = (unsigned)f2bf(acc0[dt]) | ((unsigned)f2bf(acc1[dt]) << 16);
        *(unsigned*)(out + (size_t)(b * 1024 + t0 + dt) * 1024 + c) = o;
    }
}

static inline void launch_gemm(const bf16u* A, const bf16u* Wt, const void* bias,
                               const float* res, void* C, int M, int N, int K,
                               float alpha, int act, int outbf, const int* flagp,
                               hipStream_t stream)
{
    dim3 grid(N / 128, M / 128);
    gemm_mfma<<<grid, 256, 0, stream>>>(A, Wt, bias, res, C, M, N, K, alpha, act, outbf, flagp);
}

extern "C" void kernel_launch(void* const* d_in, const int* in_sizes, int n_in,
                              void* d_out, int out_size, void* d_ws, size_t ws_size,
                              hipStream_t stream)
{
    const void* x       = d_in[0];
    const void* pos_emb = d_in[1];
    const void* ln1_g   = d_in[2];
    const void* ln1_b   = d_in[3];
    const void* ffn1_w1 = d_in[4];
    const void* ffn1_b1 = d_in[5];
    const void* ffn1_w2 = d_in[6];
    const void* ffn1_b2 = d_in[7];
    const void* lnq_g   = d_in[8];
    const void* lnq_b   = d_in[9];
    const void* lnk_g   = d_in[10];
    const void* lnk_b   = d_in[11];
    const void* lnv_g   = d_in[12];
    const void* lnv_b   = d_in[13];
    const void* wq      = d_in[14];
    const void* wk      = d_in[15];
    const void* wv      = d_in[16];
    const void* wpos    = d_in[17];
    const void* pbu     = d_in[18];
    const void* pbv     = d_in[19];
    const void* wfc     = d_in[20];
    const void* cln_g   = d_in[21];
    const void* cln_b   = d_in[22];
    const void* pw1     = d_in[23];
    const void* dw_w    = d_in[24];
    const void* bn_g    = d_in[25];
    const void* bn_b    = d_in[26];
    const void* pw2     = d_in[27];
    const void* ln2_g   = d_in[28];
    const void* ln2_b   = d_in[29];
    const void* ffn2_w1 = d_in[30];
    const void* ffn2_b1 = d_in[31];
    const void* ffn2_w2 = d_in[32];
    const void* ffn2_b2 = d_in[33];
    const void* lnf_g   = d_in[34];
    const void* lnf_b   = d_in[35];

    const int BT = 8192;
    char* wsb = (char*)d_ws;
    float* act  = (float*)(wsb + 0);              // [8192,512] fp32 16MB, live all
    bf16u* qb   = (bf16u*)(wsb + 16777216);       // 8MB
    bf16u* kb   = (bf16u*)(wsb + 25165824);       // 8MB
    bf16u* vb   = (bf16u*)(wsb + 33554432);       // 8MB
    bf16u* pb   = (bf16u*)(wsb + 41943040);       // [1024,512] 1MB
    bf16u* tmpb = (bf16u*)(wsb + 42991616);       // [8192,512] 8MB LN out / obb
    bf16u* qu   = (bf16u*)(wsb + 51380224);       // 8MB
    bf16u* qv   = (bf16u*)(wsb + 59768832);       // 8MB
    bf16u* vt   = (bf16u*)(wsb + 68157440);       // [b][h][64][1024] 8MB
    bf16u* S    = (bf16u*)(wsb + 76546048);       // [8h,1024,1024] bf16 16MB per-b
    bf16u* BD   = (bf16u*)(wsb + 93323264);       // 16MB per-b
    bf16u* wc   = (bf16u*)(wsb + 110100480);      // weight cache 13.5MB
    int* flagp  = (int*)(wsb + 124256256);
    bf16u* obb  = tmpb;
    // phase-overlapped aliases (conv/FFN, after attention buffers die):
    bf16u* hbf  = (bf16u*)(wsb + 51380224);       // [8192,2048] bf16 32MB (over qu..S-start)
    bf16u* Gbf  = (bf16u*)(wsb + 84934656);       // [8192,1024] 16MB (over S-end/BD)
    bf16u* DWbf = (bf16u*)(wsb + 16777216);       // 16MB (over qb/kb)
    bf16u* LObf = (bf16u*)(wsb + 33554432);       // 16MB (over vb/pb/tmpb-start)

    bf16u* w_ffn1_1 = wc + 0;        // [2048,512]
    bf16u* w_ffn1_2 = wc + 1048576;  // [512,2048]
    bf16u* w_q      = wc + 2097152;
    bf16u* w_k      = wc + 2359296;
    bf16u* w_v      = wc + 2621440;
    bf16u* w_pos    = wc + 2883584;
    bf16u* w_fc     = wc + 3145728;
    bf16u* w_pw1    = wc + 3407872;  // [2048,512]
    bf16u* w_pw2    = wc + 4456448;  // [512,1024]
    bf16u* w_ffn2_1 = wc + 4980736;
    bf16u* w_ffn2_2 = wc + 6029312;

    // ---- dtype detection ----
    init_flag_kernel<<<1, 64, 0, stream>>>(flagp);
    detect_kernel<<<256, 256, 0, stream>>>(x, in_sizes[0], flagp);

    // ---- transposed bf16 weight cache ----
    wtrans_kernel<<<dim3(64, 16), 256, 0, stream>>>(ffn1_w1, w_ffn1_1, 512, 2048, flagp);
    wtrans_kernel<<<dim3(16, 64), 256, 0, stream>>>(ffn1_w2, w_ffn1_2, 2048, 512, flagp);
    wtrans_kernel<<<dim3(16, 16), 256, 0, stream>>>(wq, w_q, 512, 512, flagp);
    wtrans_kernel<<<dim3(16, 16), 256, 0, stream>>>(wk, w_k, 512, 512, flagp);
    wtrans_kernel<<<dim3(16, 16), 256, 0, stream>>>(wv, w_v, 512, 512, flagp);
    wtrans_kernel<<<dim3(16, 16), 256, 0, stream>>>(wpos, w_pos, 512, 512, flagp);
    wtrans_kernel<<<dim3(16, 16), 256, 0, stream>>>(wfc, w_fc, 512, 512, flagp);
    wtrans_kernel<<<dim3(64, 16), 256, 0, stream>>>(pw1, w_pw1, 512, 2048, flagp);
    wtrans_kernel<<<dim3(16, 32), 256, 0, stream>>>(pw2, w_pw2, 1024, 512, flagp);
    wtrans_kernel<<<dim3(64, 16), 256, 0, stream>>>(ffn2_w1, w_ffn2_1, 512, 2048, flagp);
    wtrans_kernel<<<dim3(16, 64), 256, 0, stream>>>(ffn2_w2, w_ffn2_2, 2048, 512, flagp);

    // ---- P = pos_emb @ wpos ----
    cvt_bf_kernel<<<2048, 256, 0, stream>>>(pos_emb, tmpb, 524288, flagp);
    launch_gemm(tmpb, w_pos, nullptr, nullptr, pb, 1024, 512, 512, 1.0f, 0, 1, flagp, stream);

    // ---- FFN1 half-step ----
    ln_kernel<512, 1, 0, false, true><<<BT, 256, 0, stream>>>(x, ln1_g, ln1_b, tmpb, act, flagp);
    launch_gemm(tmpb, w_ffn1_1, ffn1_b1, nullptr, hbf, BT, 2048, 512, 1.0f, 1, 1, flagp, stream);
    launch_gemm(hbf, w_ffn1_2, ffn1_b2, act, act, BT, 512, 2048, 0.5f, 0, 0, flagp, stream);

    // ---- MHSA projections ----
    ln_kernel<512, 0, 0, false, false><<<BT, 256, 0, stream>>>(act, lnq_g, lnq_b, tmpb, nullptr, flagp);
    launch_gemm(tmpb, w_q, nullptr, nullptr, qb, BT, 512, 512, 1.0f, 0, 1, flagp, stream);
    ln_kernel<512, 0, 0, false, false><<<BT, 256, 0, stream>>>(act, lnk_g, lnk_b, tmpb, nullptr, flagp);
    launch_gemm(tmpb, w_k, nullptr, nullptr, kb, BT, 512, 512, 1.0f, 0, 1, flagp, stream);
    ln_kernel<512, 0, 0, false, false><<<BT, 256, 0, stream>>>(act, lnv_g, lnv_b, tmpb, nullptr, flagp);
    launch_gemm(tmpb, w_v, nullptr, nullptr, vb, BT, 512, 512, 1.0f, 0, 1, flagp, stream);

    // ---- attention prep ----
    add_qbias_kernel<<<16384, 256, 0, stream>>>(qb, pbu, pbv, qu, qv, flagp);
    vtrans_kernel<<<dim3(32, 16, 8), 256, 0, stream>>>(vb, vt);

    // ---- attention per batch ----
    for (int b = 0; b < 8; ++b) {
        const bf16u* qu_b = qu + (size_t)b * 524288;
        const bf16u* qv_b = qv + (size_t)b * 524288;
        const bf16u* kb_b = kb + (size_t)b * 524288;
        const bf16u* vt_b = vt + (size_t)b * 524288;
        bf16u* ob_b = obb + (size_t)b * 524288;
        attn_score_mfma<<<dim3(8, 8, 16), 256, 0, stream>>>(qu_b, qv_b, kb_b, pb, S, BD);
        attn_softmax_kernel<<<dim3(1024, 8), 256, 0, stream>>>(S, BD);
        attn_pv_mfma<<<dim3(16, 8), 256, 0, stream>>>(S, vt_b, ob_b);
    }
    launch_gemm(obb, w_fc, nullptr, act, act, BT, 512, 512, 1.0f, 0, 0, flagp, stream);

    // ---- convolution module ----
    ln_kernel<512, 0, 0, false, false><<<BT, 256, 0, stream>>>(act, cln_g, cln_b, tmpb, nullptr, flagp);
    launch_gemm(tmpb, w_pw1, nullptr, nullptr, hbf, BT, 2048, 512, 1.0f, 0, 1, flagp, stream);
    glu_kernel<<<32768, 256, 0, stream>>>(hbf, Gbf, 8388608);
    dwconv_kernel<<<2048, 256, 0, stream>>>(Gbf, dw_w, DWbf, flagp);
    ln_kernel<1024, 2, 0, true, false><<<BT, 256, 0, stream>>>(DWbf, bn_g, bn_b, LObf, nullptr, flagp);
    launch_gemm(LObf, w_pw2, nullptr, act, act, BT, 512, 1024, 1.0f, 0, 0, flagp, stream);

    // ---- FFN2 half-step ----
    ln_kernel<512, 0, 0, false, false><<<BT, 256, 0, stream>>>(act, ln2_g, ln2_b, tmpb, nullptr, flagp);
    launch_gemm(tmpb, w_ffn2_1, ffn2_b1, nullptr, hbf, BT, 2048, 512, 1.0f, 1, 1, flagp, stream);
    launch_gemm(hbf, w_ffn2_2, ffn2_b2, act, act, BT, 512, 2048, 0.5f, 0, 0, flagp, stream);

    // ---- final LN -> d_out ----
    ln_kernel<512, 0, 1, false, false><<<BT, 256, 0, stream>>>(act, lnf_g, lnf_b, d_out, nullptr, flagp);
}